// Round 16
// baseline (1064.092 us; speedup 1.0000x reference)
//
#include <hip/hip_runtime.h>

#define B_ 16
#define L_ 4096
#define DK_ 64
#define R_ 4
#define NB_ 64
#define BL_ 64
#define MAXFLAG 65536
#define THRESH 4e-3f

typedef __attribute__((ext_vector_type(8))) short bf16x8;
typedef __attribute__((ext_vector_type(4))) float f32x4;

__device__ __forceinline__ float bf2f(unsigned short u) {
  return __uint_as_float(((unsigned)u) << 16);
}
// HW packed f32->bf16 (RNE) — 1 inst per 2 values
__device__ __forceinline__ unsigned cvtpk(float lo, float hi) {
  unsigned r;
  asm("v_cvt_pk_bf16_f32 %0, %1, %2" : "=v"(r) : "v"(lo), "v"(hi));
  return r;
}
__device__ __forceinline__ int swz(int row) { return (row & 7) ^ ((row >> 3) & 7); }

// ---- Kernel 0: zero the flag counter ----------------------------------------
__global__ void zc_kernel(int* cnt) { *cnt = 0; }

// ---- Kernel 1: LSH hashing — fp32 fast path + margin flagging ---------------
// R15 structure (2x16 tile, two half-d rs passes, 39.4KB LDS) but all-fp32.
// Decisions with top-2 margin < THRESH are appended to flaglist for exact
// fp64 fixup. Emits Qn bf16 + qscale + Vb (identical to R15).
__global__ __launch_bounds__(256) void hash_kernel(
    const float* __restrict__ query, const float* __restrict__ value,
    const float* __restrict__ rm, int* __restrict__ bucket,
    unsigned short* __restrict__ Qn, float* __restrict__ qscale,
    unsigned short* __restrict__ Vb,
    int* __restrict__ cnt, int* __restrict__ flaglist) {
  __shared__ float qs[64 * 68];      // q[tok][d], stride 68   (17408B)
  __shared__ float rs[32 * 160];     // rm half-d [32][cg*20]  (20480B)
  __shared__ float ssinf[128];       // (512B)
  __shared__ int sb[64 * 4];         // (1024B)

  int b = blockIdx.x >> 6;
  int tok0 = (blockIdx.x & 63) << 6;   // 64 tokens per block
  int t = threadIdx.x;

  {  // stage q: 64 tok x 16 float4
    const float4* qg = (const float4*)(query + ((size_t)b * L_ + tok0) * DK_);
    #pragma unroll
    for (int u = 0; u < 4; ++u) {
      int i = t + u * 256;
      int tokl = i >> 4, c4 = i & 15;
      *(float4*)(qs + tokl * 68 + c4 * 4) = qg[i];
    }
  }
  {  // stage rm rows d = 0..31 into padded-cg layout
    const float4* rg = (const float4*)(rm + (size_t)b * (DK_ * 128));
    #pragma unroll
    for (int u = 0; u < 4; ++u) {
      int i = t + u * 256;
      int d = i >> 5, c4 = i & 31;
      int cg2 = c4 >> 2, j4 = c4 & 3;
      *(float4*)(rs + d * 160 + cg2 * 20 + j4 * 4) = rg[i];
    }
  }
  __syncthreads();

  // ssin partial over d = 0..31 (fp32)
  float ssp = 0.f;
  if (t < 128) {
    const float* colp = rs + (t >> 4) * 20 + (t & 15);
    for (int d = 0; d < 32; ++d) {
      float v = colp[d * 160];
      ssp += v * v;
    }
  }

  int cg = t & 7;
  int tg = t >> 3;
  float acc0[16], acc1[16];
  #pragma unroll
  for (int j = 0; j < 16; ++j) { acc0[j] = 0.f; acc1[j] = 0.f; }

  const float* q0 = qs + (tg * 2 + 0) * 68;
  const float* q1 = qs + (tg * 2 + 1) * 68;
  const float* rp = rs + cg * 20;

  // ---- acc part 1: d = 0..31 ----
  for (int d4 = 0; d4 < 8; ++d4) {
    float4 qa4 = *(const float4*)(q0 + d4 * 4);
    float4 qb4 = *(const float4*)(q1 + d4 * 4);
    #pragma unroll
    for (int sub = 0; sub < 4; ++sub) {
      float qa = (sub == 0) ? qa4.x : (sub == 1) ? qa4.y : (sub == 2) ? qa4.z : qa4.w;
      float qb = (sub == 0) ? qb4.x : (sub == 1) ? qb4.y : (sub == 2) ? qb4.z : qb4.w;
      const float* rr = rp + (d4 * 4 + sub) * 160;
      #pragma unroll
      for (int j4 = 0; j4 < 4; ++j4) {
        float4 rv = *(const float4*)(rr + j4 * 4);
        acc0[j4 * 4 + 0] += qa * rv.x; acc0[j4 * 4 + 1] += qa * rv.y;
        acc0[j4 * 4 + 2] += qa * rv.z; acc0[j4 * 4 + 3] += qa * rv.w;
        acc1[j4 * 4 + 0] += qb * rv.x; acc1[j4 * 4 + 1] += qb * rv.y;
        acc1[j4 * 4 + 2] += qb * rv.z; acc1[j4 * 4 + 3] += qb * rv.w;
      }
    }
  }
  __syncthreads();   // everyone done reading rs half 1

  {  // stage rm rows d = 32..63
    const float4* rg = (const float4*)(rm + (size_t)b * (DK_ * 128)) + 1024;
    #pragma unroll
    for (int u = 0; u < 4; ++u) {
      int i = t + u * 256;
      int d = i >> 5, c4 = i & 31;
      int cg2 = c4 >> 2, j4 = c4 & 3;
      *(float4*)(rs + d * 160 + cg2 * 20 + j4 * 4) = rg[i];
    }
  }
  __syncthreads();

  // ssin finish over d = 32..63
  if (t < 128) {
    const float* colp = rs + (t >> 4) * 20 + (t & 15);
    for (int d = 0; d < 32; ++d) {
      float v = colp[d * 160];
      ssp += v * v;
    }
    ssinf[t] = 1.0f / sqrtf(ssp);
  }

  // ---- acc part 2: d = 32..63 (rs rows hold d-32) ----
  for (int d4 = 8; d4 < 16; ++d4) {
    float4 qa4 = *(const float4*)(q0 + d4 * 4);
    float4 qb4 = *(const float4*)(q1 + d4 * 4);
    #pragma unroll
    for (int sub = 0; sub < 4; ++sub) {
      float qa = (sub == 0) ? qa4.x : (sub == 1) ? qa4.y : (sub == 2) ? qa4.z : qa4.w;
      float qb = (sub == 0) ? qb4.x : (sub == 1) ? qb4.y : (sub == 2) ? qb4.z : qb4.w;
      const float* rr = rp + ((d4 - 8) * 4 + sub) * 160;
      #pragma unroll
      for (int j4 = 0; j4 < 4; ++j4) {
        float4 rv = *(const float4*)(rr + j4 * 4);
        acc0[j4 * 4 + 0] += qa * rv.x; acc0[j4 * 4 + 1] += qa * rv.y;
        acc0[j4 * 4 + 2] += qa * rv.z; acc0[j4 * 4 + 3] += qa * rv.w;
        acc1[j4 * 4 + 0] += qb * rv.x; acc1[j4 * 4 + 1] += qb * rv.y;
        acc1[j4 * 4 + 2] += qb * rv.z; acc1[j4 * 4 + 3] += qb * rv.w;
      }
    }
  }
  __syncthreads();   // ssinf final visible to all

  // ---- top-2 argmax (fp32) with margin tracking ----
  float bv0 = -1e30f, bs0 = -1e30f;
  float bv1 = -1e30f, bs1 = -1e30f;
  int bi0 = 0, bi1 = 0;
  int nbase = (cg & 1) * 16;
  #pragma unroll
  for (int j = 0; j < 16; ++j) {
    int col = cg * 16 + j;
    float sv = ssinf[col];
    int n = nbase + j;
    float v0 = acc0[j] * sv;
    float v1 = acc1[j] * sv;
    if (v0 > bv0) { bs0 = bv0; bv0 = v0; bi0 = n; } else if (v0 > bs0) bs0 = v0;
    float w0 = -v0;
    if (w0 > bv0) { bs0 = bv0; bv0 = w0; bi0 = n + 32; } else if (w0 > bs0) bs0 = w0;
    if (v1 > bv1) { bs1 = bv1; bv1 = v1; bi1 = n; } else if (v1 > bs1) bs1 = v1;
    float w1 = -v1;
    if (w1 > bv1) { bs1 = bv1; bv1 = w1; bi1 = n + 32; } else if (w1 > bs1) bs1 = w1;
  }
  {  // merge the two half-round threads (cg even/odd), keeping top-2
    float ov, os; int oi;
    ov = __shfl_xor(bv0, 1); os = __shfl_xor(bs0, 1); oi = __shfl_xor(bi0, 1);
    if (ov > bv0) { bs0 = fmaxf(bv0, os); bv0 = ov; bi0 = oi; }
    else          { bs0 = fmaxf(bs0, ov); }
    ov = __shfl_xor(bv1, 1); os = __shfl_xor(bs1, 1); oi = __shfl_xor(bi1, 1);
    if (ov > bv1) { bs1 = fmaxf(bv1, os); bv1 = ov; bi1 = oi; }
    else          { bs1 = fmaxf(bs1, ov); }
  }
  if ((cg & 1) == 0) {
    int rr_ = cg >> 1;
    sb[(tg * 2 + 0) * 4 + rr_] = bi0;
    sb[(tg * 2 + 1) * 4 + rr_] = bi1;
    if (bv0 - bs0 < THRESH) {
      int ix = atomicAdd(cnt, 1);
      if (ix < MAXFLAG) flaglist[ix] = (b << 14) | ((tok0 + tg * 2 + 0) << 2) | rr_;
    }
    if (bv1 - bs1 < THRESH) {
      int ix = atomicAdd(cnt, 1);
      if (ix < MAXFLAG) flaglist[ix] = (b << 14) | ((tok0 + tg * 2 + 1) << 2) | rr_;
    }
  }
  __syncthreads();
  if (t < 64)
    ((int4*)bucket)[(size_t)b * L_ + tok0 + t] = ((int4*)sb)[t];

  // ---- emit normalized bf16 Q rows + scale (exact same reduction order) ----
  if (t < 128) {
    int row = t >> 1, half = t & 1;
    const float* qp = qs + row * 68 + half * 32;
    float v[32];
    float ss = 0.f;
    #pragma unroll
    for (int u = 0; u < 8; ++u) {
      float4 x = *(const float4*)(qp + u * 4);
      v[u*4+0] = x.x; v[u*4+1] = x.y; v[u*4+2] = x.z; v[u*4+3] = x.w;
      ss += x.x*x.x + x.y*x.y + x.z*x.z + x.w*x.w;
    }
    ss += __shfl_xor(ss, 1);
    float inv = 1.0f / fmaxf(sqrtf(ss), 1e-12f);
    unsigned short* qn = Qn + ((size_t)b * L_ + tok0 + row) * 64 + half * 32;
    #pragma unroll
    for (int u = 0; u < 4; ++u) {
      uint4 pk;
      pk.x = cvtpk(v[u*8+0] * inv, v[u*8+1] * inv);
      pk.y = cvtpk(v[u*8+2] * inv, v[u*8+3] * inv);
      pk.z = cvtpk(v[u*8+4] * inv, v[u*8+5] * inv);
      pk.w = cvtpk(v[u*8+6] * inv, v[u*8+7] * inv);
      ((uint4*)qn)[u] = pk;
    }
    if (half == 0)
      qscale[(size_t)b * L_ + tok0 + row] = 0.18033688f / inv;  // 0.125*log2e*|q|
  }

  // ---- convert this block's V rows to bf16 (adjacent-pair cvtpk) ----
  {
    int row = t >> 2, qd = t & 3;
    const float* vr = value + ((size_t)b * L_ + tok0 + row) * DK_ + qd * 16;
    float4 x0 = ((const float4*)vr)[0], x1 = ((const float4*)vr)[1],
           x2 = ((const float4*)vr)[2], x3 = ((const float4*)vr)[3];
    uint4 p0, p1;
    p0.x = cvtpk(x0.x, x0.y); p0.y = cvtpk(x0.z, x0.w);
    p0.z = cvtpk(x1.x, x1.y); p0.w = cvtpk(x1.z, x1.w);
    p1.x = cvtpk(x2.x, x2.y); p1.y = cvtpk(x2.z, x2.w);
    p1.z = cvtpk(x3.x, x3.y); p1.w = cvtpk(x3.z, x3.w);
    unsigned short* out = Vb + ((size_t)b * L_ + tok0 + row) * 64 + qd * 16;
    ((uint4*)out)[0] = p0;
    ((uint4*)out)[1] = p1;
  }
}

// ---- Kernel 1.5: exact fp64 fixup for margin-flagged decisions --------------
// One wave per flagged (b,l,r). Lane n<32: +col n; lane>=32: -col (n-32).
// Same d-ascending fp64 chains as the historical fp64 hash -> bit-identical.
__global__ __launch_bounds__(64) void fixup_kernel(
    const float* __restrict__ query, const float* __restrict__ rm,
    const int* __restrict__ flaglist, const int* __restrict__ cnt,
    int* __restrict__ bucket) {
  int nfl = *cnt;
  if (nfl > MAXFLAG) nfl = MAXFLAG;
  int lane = threadIdx.x;
  for (int i = blockIdx.x; i < nfl; i += gridDim.x) {
    int code = flaglist[i];
    int r = code & 3, l = (code >> 2) & 4095, b = code >> 14;
    int col = r * 32 + (lane & 31);
    const float* qrow = query + ((size_t)b * L_ + l) * DK_;
    const float* rmc = rm + (size_t)b * (DK_ * 128) + col;
    double acc = 0.0, ss = 0.0;
    for (int d = 0; d < DK_; ++d) {
      double qv = (double)qrow[d];
      double rv = (double)rmc[d * 128];
      acc += qv * rv;
      ss += rv * rv;
    }
    double sinv = 1.0 / sqrt(ss);
    double v = acc * sinv;
    double bv = (lane < 32) ? v : -v;
    int bi = lane;
    #pragma unroll
    for (int msk = 1; msk < 64; msk <<= 1) {
      double ov = __shfl_xor(bv, msk);
      int oi = __shfl_xor(bi, msk);
      if (ov > bv || (ov == bv && oi < bi)) { bv = ov; bi = oi; }
    }
    if (lane == 0) bucket[((size_t)b * L_ + l) * 4 + r] = bi;
  }
}

// ------- Kernel 2: 16-wave two-level stable counting sort per (b, r) --------
__global__ __launch_bounds__(1024) void sort_kernel(
    const int* __restrict__ bucket, int* __restrict__ sorted_pos,
    unsigned char* __restrict__ cpack) {
  int b = blockIdx.x >> 2;
  int r = blockIdx.x & 3;
  __shared__ int hist[64 * 65];   // [chunk][bin], stride 65
  __shared__ int off[64];
  int t = threadIdx.x, lane = t & 63, w = t >> 6;
  unsigned long long ltmask = (1ull << lane) - 1ull;
  const int* bb = bucket + (size_t)b * L_ * 4 + r;

  int binv[4], rank[4];
  #pragma unroll
  for (int u = 0; u < 4; ++u)
    binv[u] = bb[(size_t)((w * 4 + u) * 64 + lane) * 4];

  for (int idx = t; idx < 64 * 65; idx += 1024) hist[idx] = 0;
  __syncthreads();

  #pragma unroll
  for (int u = 0; u < 4; ++u) {
    int bin = binv[u];
    unsigned long long m = ~0ull;
    #pragma unroll
    for (int k = 0; k < 6; ++k) {
      unsigned long long bal = __ballot((bin >> k) & 1);
      m &= ((bin >> k) & 1) ? bal : ~bal;
    }
    rank[u] = (int)__popcll(m & ltmask);
    if (rank[u] == 0) hist[(w * 4 + u) * 65 + bin] = (int)__popcll(m);
  }
  __syncthreads();

  if (w == 0) {
    int run = 0;
    for (int g = 0; g < 64; ++g) {
      int v = hist[g * 65 + lane];
      hist[g * 65 + lane] = run;
      run += v;
    }
    int inc = run;
    #pragma unroll
    for (int d = 1; d < 64; d <<= 1) {
      int y = __shfl_up(inc, d, 64);
      if (lane >= d) inc += y;
    }
    off[lane] = inc - run;
  }
  __syncthreads();

  int* sp = sorted_pos + ((size_t)b * R_ + r) * L_;
  unsigned char* cp = cpack + (size_t)b * L_ * 4 + r;
  #pragma unroll
  for (int u = 0; u < 4; ++u) {
    int g = w * 4 + u;
    int bin = binv[u];
    int slot = off[bin] + hist[g * 65 + bin] + rank[u];
    sp[slot] = g * 64 + lane;
    cp[(size_t)(g * 64 + lane) * 4] = (unsigned char)(slot >> 6);
  }
}

// ---------------- Kernel 3: per-chunk attention (bf16 MFMA, R11 form) --------
__global__ __launch_bounds__(256) void attn_kernel(
    const unsigned short* __restrict__ Qn, const unsigned short* __restrict__ Vb,
    const float* __restrict__ qscale,
    const int* __restrict__ sorted_pos, const int* __restrict__ bucket,
    const int* __restrict__ cpack,
    unsigned short* __restrict__ att, float* __restrict__ lse_s) {
  int wg = (int)blockIdx.x;
  wg = (wg & 7) * (B_ * R_ * NB_ / 8) + (wg >> 3);   // XCD-contiguous swizzle
  int n = wg & 63;
  int r = (wg >> 6) & 3;
  int b = wg >> 8;
  int br = b * R_ + r;
  int nprev = (n + 63) & 63;

  __shared__ __align__(16) short bufK[128 * 64];   // K_norm bf16; reused as VT[64][128]
  __shared__ int skpos[128];
  __shared__ int skcode[128];                      // (bucket<<12) | pos
  __shared__ int sck[128];                         // packed chunk ids (4x8b)

  int t = threadIdx.x;
  if (t < 128) {
    int chunk = (t < 64) ? nprev : n;
    int pos = sorted_pos[(size_t)br * L_ + chunk * 64 + (t & 63)];
    skpos[t] = pos;
    skcode[t] = (bucket[((size_t)b * L_ + pos) * 4 + r] << 12) | pos;
    sck[t] = ((const int*)cpack)[(size_t)b * L_ + pos];
  }
  __syncthreads();

  int l = t & 63, w = t >> 6;
  int g = l >> 4, c = l & 15;
  int qi = w * 16 + c;

  // ---- K staging from Qn (bf16, swizzled LDS image) ----
  {
    int j = t >> 1, half = t & 1;
    const uint4* src = (const uint4*)(Qn + ((size_t)b * L_ + skpos[j]) * 64 + half * 32);
    short* krow = bufK + j * 64;
    int sz = swz(j);
    #pragma unroll
    for (int u = 0; u < 4; ++u)
      *(uint4*)(krow + (((half * 4 + u) ^ sz) << 3)) = src[u];
  }
  int qcode = skcode[64 + qi];
  int qpos = qcode & 4095;
  float csc = qscale[(size_t)b * L_ + qpos];   // issued early; used post-QK
  __syncthreads();

  // ---- QK^T via MFMA, SWAPPED: D = K_frag · Q_frag = S^T ----
  f32x4 acc[8];
  #pragma unroll
  for (int tt = 0; tt < 8; ++tt) acc[tt] = (f32x4){0.f, 0.f, 0.f, 0.f};
  {
    int qrow = 64 + qi;
    const short* qp_ = bufK + qrow * 64;
    bf16x8 q0 = *(const bf16x8*)(qp_ + (((g) ^ swz(qrow)) << 3));
    bf16x8 q1 = *(const bf16x8*)(qp_ + (((4 + g) ^ swz(qrow)) << 3));
    #pragma unroll
    for (int tt = 0; tt < 8; ++tt) {
      int krow = tt * 16 + c;
      const short* kp_ = bufK + krow * 64;
      bf16x8 k0 = *(const bf16x8*)(kp_ + (((g) ^ swz(krow)) << 3));
      bf16x8 k1 = *(const bf16x8*)(kp_ + (((4 + g) ^ swz(krow)) << 3));
      acc[tt] = __builtin_amdgcn_mfma_f32_16x16x32_bf16(k0, q0, acc[tt], 0, 0, 0);
      acc[tt] = __builtin_amdgcn_mfma_f32_16x16x32_bf16(k1, q1, acc[tt], 0, 0, 0);
    }
  }
  __syncthreads();   // all waves done reading bufK (VT will overwrite)

  // ---- issue V gathers early (bf16); consumed after softmax ----
  int pi = t >> 2, qd = t & 3;
  const uint4* vr0 = (const uint4*)(Vb + ((size_t)b * L_ + skpos[2 * pi]) * 64 + qd * 16);
  const uint4* vr1 = (const uint4*)(Vb + ((size_t)b * L_ + skpos[2 * pi + 1]) * 64 + qd * 16);
  uint4 A0 = vr0[0], A1 = vr0[1];
  uint4 B0 = vr1[0], B1 = vr1[1];

  // ---- masks + lane-local softmax (exp2 domain) ----
  unsigned aq = (unsigned)sck[64 + qi] | 0x40404040u;

  float m = -1e30f;
  #pragma unroll
  for (int tt = 0; tt < 8; ++tt) {
    int4 kc = *(const int4*)(skcode + tt * 16 + g * 4);
    #pragma unroll
    for (int j = 0; j < 4; ++j) {
      int kcode = (j == 0) ? kc.x : (j == 1) ? kc.y : (j == 2) ? kc.z : kc.w;
      float s = acc[tt][j] * csc;
      unsigned x = (unsigned)(qcode ^ kcode);
      s = ((qcode < kcode) || (x >= 4096u)) ? -1e9f : s;
      s = (x == 0u) ? -144269.5f : s;   // -1e5 * log2e
      acc[tt][j] = s;
      m = fmaxf(m, s);
    }
  }
  m = fmaxf(m, __shfl_xor(m, 16));
  m = fmaxf(m, __shfl_xor(m, 32));
  float sum = 0.f;
  #pragma unroll
  for (int tt = 0; tt < 8; ++tt) {
    #pragma unroll
    for (int j = 0; j < 4; ++j) {
      float e = exp2f(acc[tt][j] - m);
      acc[tt][j] = e;
      sum += e;
    }
  }
  sum += __shfl_xor(sum, 16);
  sum += __shfl_xor(sum, 32);
  float lse = 0.69314718f * (m + __log2f(sum));
  float isum = 1.0f / sum;
  if (l < 16) lse_s[(size_t)br * L_ + qpos] = lse;

  // ---- dup-count (SWAR) -> final P in registers ----
  #pragma unroll
  for (int tt = 0; tt < 8; ++tt) {
    int4 c4v = *(const int4*)(sck + tt * 16 + g * 4);
    #pragma unroll
    for (int j = 0; j < 4; ++j) {
      int ckv = (j == 0) ? c4v.x : (j == 1) ? c4v.y : (j == 2) ? c4v.z : c4v.w;
      unsigned e = (aq - (unsigned)ckv) & 0x3E3E3E3Eu;
      unsigned y = (e - 0x01010101u) & ~e & 0x80808080u;
      float cntf = (float)__popc(y);
      acc[tt][j] = acc[tt][j] * isum * __builtin_amdgcn_rcpf(cntf);
    }
  }

  // ---- P -> bf16 pairs in registers ----
  unsigned pk01[8], pk23[8];
  #pragma unroll
  for (int tt = 0; tt < 8; ++tt) {
    pk01[tt] = cvtpk(acc[tt][0], acc[tt][1]);
    pk23[tt] = cvtpk(acc[tt][2], acc[tt][3]);
  }

  // ---- VT staging into freed bufK (transpose from bf16 regs) ----
  short* VT = bufK;
  {
    unsigned Aw[8] = {A0.x, A0.y, A0.z, A0.w, A1.x, A1.y, A1.z, A1.w};
    unsigned Bw[8] = {B0.x, B0.y, B0.z, B0.w, B1.x, B1.y, B1.z, B1.w};
    int k0 = 2 * pi;
    #pragma unroll
    for (int i = 0; i < 8; ++i) {
      unsigned lo = (Aw[i] & 0xffffu) | (Bw[i] << 16);
      unsigned hi = (Aw[i] >> 16) | (Bw[i] & 0xffff0000u);
      int dl = qd * 16 + 2 * i, dh = dl + 1;
      *(unsigned*)(VT + dl * 128 + (((k0 >> 3) ^ swz(dl)) << 3) + (k0 & 7)) = lo;
      *(unsigned*)(VT + dh * 128 + (((k0 >> 3) ^ swz(dh)) << 3) + (k0 & 7)) = hi;
    }
  }
  __syncthreads();

  // ---- PV via MFMA: O^T[d][q] = sum_k VT[d][k] * P^T[k][q] ----
  f32x4 o[4];
  #pragma unroll
  for (int nt = 0; nt < 4; ++nt) o[nt] = (f32x4){0.f, 0.f, 0.f, 0.f};
  {
    int src  = (g & 1) * 32 + c;
    int srcB = src + 16;
    bool sel = (l >= 32);
    #pragma unroll
    for (int ks = 0; ks < 4; ++ks) {
      unsigned xA = __shfl(pk01[2 * ks], src),  yA = __shfl(pk01[2 * ks + 1], src);
      unsigned xB = __shfl(pk23[2 * ks], src),  yB = __shfl(pk23[2 * ks + 1], src);
      unsigned xC = __shfl(pk01[2 * ks], srcB), yC = __shfl(pk01[2 * ks + 1], srcB);
      unsigned xD = __shfl(pk23[2 * ks], srcB), yD = __shfl(pk23[2 * ks + 1], srcB);
      union { uint4 u; bf16x8 v; } bp;
      bp.u.x = sel ? yA : xA;
      bp.u.y = sel ? yB : xB;
      bp.u.z = sel ? yC : xC;
      bp.u.w = sel ? yD : xD;
      #pragma unroll
      for (int nt = 0; nt < 4; ++nt) {
        int vrow = nt * 16 + c;
        bf16x8 av = *(const bf16x8*)(VT + vrow * 128 + (((ks * 4 + g) ^ swz(vrow)) << 3));
        o[nt] = __builtin_amdgcn_mfma_f32_16x16x32_bf16(av, bp.v, o[nt], 0, 0, 0);
      }
    }
  }

  // ---- scatter att rows (bf16, 8B stores): lane owns one q-row ----
  {
    unsigned short* arow = att + ((size_t)br * L_ + qpos) * DK_;
    #pragma unroll
    for (int nt = 0; nt < 4; ++nt) {
      unsigned p0 = cvtpk(o[nt][0], o[nt][1]);
      unsigned p1 = cvtpk(o[nt][2], o[nt][3]);
      *(uint2*)(arow + nt * 16 + g * 4) = make_uint2(p0, p1);
    }
  }
}

// ---------------- Kernel 4: softmax reduction over L of lse ------------------
__global__ __launch_bounds__(256) void lsered_kernel(
    const float* __restrict__ lse_s, float* __restrict__ wred) {
  int br = blockIdx.x;
  const float* row = lse_s + (size_t)br * L_;
  __shared__ float red[4];
  int t = threadIdx.x;
  float m = -1e30f;
  for (int p = t; p < L_; p += 256) m = fmaxf(m, row[p]);
  #pragma unroll
  for (int mask = 1; mask < 64; mask <<= 1) m = fmaxf(m, __shfl_xor(m, mask, 64));
  if ((t & 63) == 0) red[t >> 6] = m;
  __syncthreads();
  m = fmaxf(fmaxf(red[0], red[1]), fmaxf(red[2], red[3]));
  __syncthreads();
  float sum = 0.f;
  for (int p = t; p < L_; p += 256) sum += __expf(row[p] - m);
  #pragma unroll
  for (int mask = 1; mask < 64; mask <<= 1) sum += __shfl_xor(sum, mask, 64);
  if ((t & 63) == 0) red[t >> 6] = sum;
  __syncthreads();
  if (t == 0) {
    wred[br * 2] = m;
    wred[br * 2 + 1] = red[0] + red[1] + red[2] + red[3];
  }
}

// ---------------- Kernel 5: weighted combine over rounds ---------------------
__global__ __launch_bounds__(256) void combine_kernel(
    const unsigned short* __restrict__ att, const float* __restrict__ lse_s,
    const float* __restrict__ wred, float* __restrict__ out) {
  int idx = blockIdx.x * 256 + threadIdx.x;
  int dq = idx & 3;
  int l = (idx >> 2) & (L_ - 1);
  int b = idx >> 14;
  float wv[4];
  #pragma unroll
  for (int r = 0; r < R_; ++r) {
    float m = wred[(b * R_ + r) * 2];
    float sinv = 1.0f / wred[(b * R_ + r) * 2 + 1];
    wv[r] = __expf(lse_s[((size_t)b * R_ + r) * L_ + l] - m) * sinv;
  }
  #pragma unroll
  for (int u = 0; u < 4; ++u) {
    int d4 = dq * 4 + u;
    float4 o = make_float4(0.f, 0.f, 0.f, 0.f);
    #pragma unroll
    for (int r = 0; r < R_; ++r) {
      ushort4 a = *(const ushort4*)(att + ((((size_t)b * R_ + r) * L_ + l) * 16 + d4) * 4);
      o.x += wv[r] * bf2f(a.x); o.y += wv[r] * bf2f(a.y);
      o.z += wv[r] * bf2f(a.z); o.w += wv[r] * bf2f(a.w);
    }
    ((float4*)out)[((size_t)b * L_ + l) * 16 + d4] = o;
  }
}

extern "C" void kernel_launch(void* const* d_in, const int* in_sizes, int n_in,
                              void* d_out, int out_size, void* d_ws, size_t ws_size,
                              hipStream_t stream) {
  const float* query = (const float*)d_in[0];
  const float* value = (const float*)d_in[1];
  const float* rm    = (const float*)d_in[2];
  (void)in_sizes; (void)n_in; (void)out_size; (void)ws_size;

  char* ws = (char*)d_ws;
  const size_t ATT_BYTES = (size_t)B_ * R_ * L_ * DK_ * 2;  // 32 MiB (bf16)
  const size_t MB = 1048576;
  unsigned short* att        = (unsigned short*)ws;
  int*            bucket     = (int*)(ws + ATT_BYTES);
  int*            sorted_pos = (int*)(ws + ATT_BYTES + 1 * MB);
  unsigned char*  cpack      = (unsigned char*)(ws + ATT_BYTES + 2 * MB);
  float*          lse_s      = (float*)(ws + ATT_BYTES + 3 * MB);
  float*          wred       = (float*)(ws + ATT_BYTES + 4 * MB);
  float*          qscale     = (float*)(ws + ATT_BYTES + 6 * MB);
  unsigned short* Qn         = (unsigned short*)(ws + ATT_BYTES + 8 * MB);
  unsigned short* Vb         = (unsigned short*)(ws + ATT_BYTES + 16 * MB);
  int*            cnt        = (int*)(ws + ATT_BYTES + 24 * MB);
  int*            flaglist   = (int*)(ws + ATT_BYTES + 25 * MB);
  float* out = (float*)d_out;

  zc_kernel<<<1, 1, 0, stream>>>(cnt);
  hash_kernel<<<B_ * 64, 256, 0, stream>>>(query, value, rm, bucket, Qn, qscale,
                                           Vb, cnt, flaglist);
  fixup_kernel<<<512, 64, 0, stream>>>(query, rm, flaglist, cnt, bucket);
  sort_kernel<<<B_ * R_, 1024, 0, stream>>>(bucket, sorted_pos, cpack);
  attn_kernel<<<B_ * R_ * NB_, 256, 0, stream>>>(Qn, Vb, qscale, sorted_pos,
                                                 bucket, (const int*)cpack,
                                                 att, lse_s);
  lsered_kernel<<<B_ * R_, 256, 0, stream>>>(lse_s, wred);
  combine_kernel<<<(B_ * L_ * 4) / 256, 256, 0, stream>>>(att, lse_s, wred, out);
}

// Round 17
// 152.860 us; speedup vs baseline: 6.9612x; 6.9612x over previous
//
#include <hip/hip_runtime.h>

#define B_ 16
#define L_ 4096
#define DK_ 64
#define R_ 4
#define NB_ 64
#define BL_ 64
#define MAXFLAG 65536
#define THRESH 4e-3f

typedef __attribute__((ext_vector_type(8))) short bf16x8;
typedef __attribute__((ext_vector_type(4))) float f32x4;

__device__ __forceinline__ float bf2f(unsigned short u) {
  return __uint_as_float(((unsigned)u) << 16);
}
// HW packed f32->bf16 (RNE) — 1 inst per 2 values
__device__ __forceinline__ unsigned cvtpk(float lo, float hi) {
  unsigned r;
  asm("v_cvt_pk_bf16_f32 %0, %1, %2" : "=v"(r) : "v"(lo), "v"(hi));
  return r;
}
__device__ __forceinline__ int swz(int row) { return (row & 7) ^ ((row >> 3) & 7); }

// ---- Kernel 0: zero the flag counter ----------------------------------------
__global__ void zc_kernel(int* cnt) { *cnt = 0; }

// ---- Kernel 1: LSH hashing — fp32 fast path + BRANCHLESS top-2 + flags ------
__global__ __launch_bounds__(256) void hash_kernel(
    const float* __restrict__ query, const float* __restrict__ value,
    const float* __restrict__ rm, int* __restrict__ bucket,
    unsigned short* __restrict__ Qn, float* __restrict__ qscale,
    unsigned short* __restrict__ Vb,
    int* __restrict__ cnt, int* __restrict__ flaglist) {
  __shared__ float qs[64 * 68];      // q[tok][d], stride 68   (17408B)
  __shared__ float rs[32 * 160];     // rm half-d [32][cg*20]  (20480B)
  __shared__ float ssinf[128];       // (512B)
  __shared__ int sb[64 * 4];         // (1024B)

  int b = blockIdx.x >> 6;
  int tok0 = (blockIdx.x & 63) << 6;   // 64 tokens per block
  int t = threadIdx.x;

  {  // stage q: 64 tok x 16 float4
    const float4* qg = (const float4*)(query + ((size_t)b * L_ + tok0) * DK_);
    #pragma unroll
    for (int u = 0; u < 4; ++u) {
      int i = t + u * 256;
      int tokl = i >> 4, c4 = i & 15;
      *(float4*)(qs + tokl * 68 + c4 * 4) = qg[i];
    }
  }
  {  // stage rm rows d = 0..31 into padded-cg layout
    const float4* rg = (const float4*)(rm + (size_t)b * (DK_ * 128));
    #pragma unroll
    for (int u = 0; u < 4; ++u) {
      int i = t + u * 256;
      int d = i >> 5, c4 = i & 31;
      int cg2 = c4 >> 2, j4 = c4 & 3;
      *(float4*)(rs + d * 160 + cg2 * 20 + j4 * 4) = rg[i];
    }
  }
  __syncthreads();

  // ssin partial over d = 0..31 (fp32)
  float ssp = 0.f;
  if (t < 128) {
    const float* colp = rs + (t >> 4) * 20 + (t & 15);
    for (int d = 0; d < 32; ++d) {
      float v = colp[d * 160];
      ssp += v * v;
    }
  }

  int cg = t & 7;
  int tg = t >> 3;
  float acc0[16], acc1[16];
  #pragma unroll
  for (int j = 0; j < 16; ++j) { acc0[j] = 0.f; acc1[j] = 0.f; }

  const float* q0 = qs + (tg * 2 + 0) * 68;
  const float* q1 = qs + (tg * 2 + 1) * 68;
  const float* rp = rs + cg * 20;

  // ---- acc part 1: d = 0..31 ----
  for (int d4 = 0; d4 < 8; ++d4) {
    float4 qa4 = *(const float4*)(q0 + d4 * 4);
    float4 qb4 = *(const float4*)(q1 + d4 * 4);
    #pragma unroll
    for (int sub = 0; sub < 4; ++sub) {
      float qa = (sub == 0) ? qa4.x : (sub == 1) ? qa4.y : (sub == 2) ? qa4.z : qa4.w;
      float qb = (sub == 0) ? qb4.x : (sub == 1) ? qb4.y : (sub == 2) ? qb4.z : qb4.w;
      const float* rr = rp + (d4 * 4 + sub) * 160;
      #pragma unroll
      for (int j4 = 0; j4 < 4; ++j4) {
        float4 rv = *(const float4*)(rr + j4 * 4);
        acc0[j4 * 4 + 0] += qa * rv.x; acc0[j4 * 4 + 1] += qa * rv.y;
        acc0[j4 * 4 + 2] += qa * rv.z; acc0[j4 * 4 + 3] += qa * rv.w;
        acc1[j4 * 4 + 0] += qb * rv.x; acc1[j4 * 4 + 1] += qb * rv.y;
        acc1[j4 * 4 + 2] += qb * rv.z; acc1[j4 * 4 + 3] += qb * rv.w;
      }
    }
  }
  __syncthreads();   // everyone done reading rs half 1

  {  // stage rm rows d = 32..63
    const float4* rg = (const float4*)(rm + (size_t)b * (DK_ * 128)) + 1024;
    #pragma unroll
    for (int u = 0; u < 4; ++u) {
      int i = t + u * 256;
      int d = i >> 5, c4 = i & 31;
      int cg2 = c4 >> 2, j4 = c4 & 3;
      *(float4*)(rs + d * 160 + cg2 * 20 + j4 * 4) = rg[i];
    }
  }
  __syncthreads();

  // ssin finish over d = 32..63
  if (t < 128) {
    const float* colp = rs + (t >> 4) * 20 + (t & 15);
    for (int d = 0; d < 32; ++d) {
      float v = colp[d * 160];
      ssp += v * v;
    }
    ssinf[t] = 1.0f / sqrtf(ssp);
  }

  // ---- acc part 2: d = 32..63 (rs rows hold d-32) ----
  for (int d4 = 8; d4 < 16; ++d4) {
    float4 qa4 = *(const float4*)(q0 + d4 * 4);
    float4 qb4 = *(const float4*)(q1 + d4 * 4);
    #pragma unroll
    for (int sub = 0; sub < 4; ++sub) {
      float qa = (sub == 0) ? qa4.x : (sub == 1) ? qa4.y : (sub == 2) ? qa4.z : qa4.w;
      float qb = (sub == 0) ? qb4.x : (sub == 1) ? qb4.y : (sub == 2) ? qb4.z : qb4.w;
      const float* rr = rp + ((d4 - 8) * 4 + sub) * 160;
      #pragma unroll
      for (int j4 = 0; j4 < 4; ++j4) {
        float4 rv = *(const float4*)(rr + j4 * 4);
        acc0[j4 * 4 + 0] += qa * rv.x; acc0[j4 * 4 + 1] += qa * rv.y;
        acc0[j4 * 4 + 2] += qa * rv.z; acc0[j4 * 4 + 3] += qa * rv.w;
        acc1[j4 * 4 + 0] += qb * rv.x; acc1[j4 * 4 + 1] += qb * rv.y;
        acc1[j4 * 4 + 2] += qb * rv.z; acc1[j4 * 4 + 3] += qb * rv.w;
      }
    }
  }
  __syncthreads();   // ssinf final visible to all

  // ---- BRANCHLESS top-2 argmax (fp32): only max/min/select ----
  float bv0 = -1e30f, bs0 = -1e30f;
  float bv1 = -1e30f, bs1 = -1e30f;
  int bi0 = 0, bi1 = 0;
  int nbase = (cg & 1) * 16;
  #pragma unroll
  for (int j = 0; j < 16; ++j) {
    int col = cg * 16 + j;
    float sv = ssinf[col];
    int n = nbase + j;
    float v0 = acc0[j] * sv;
    float v1 = acc1[j] * sv;
    bs0 = fmaxf(bs0, fminf(bv0, v0));
    bi0 = (v0 > bv0) ? n : bi0;
    bv0 = fmaxf(bv0, v0);
    float w0 = -v0;
    bs0 = fmaxf(bs0, fminf(bv0, w0));
    bi0 = (w0 > bv0) ? (n + 32) : bi0;
    bv0 = fmaxf(bv0, w0);
    bs1 = fmaxf(bs1, fminf(bv1, v1));
    bi1 = (v1 > bv1) ? n : bi1;
    bv1 = fmaxf(bv1, v1);
    float w1 = -v1;
    bs1 = fmaxf(bs1, fminf(bv1, w1));
    bi1 = (w1 > bv1) ? (n + 32) : bi1;
    bv1 = fmaxf(bv1, w1);
  }
  {  // merge the two half-round threads (cg even/odd), branchless
    float ov, os; int oi;
    ov = __shfl_xor(bv0, 1); os = __shfl_xor(bs0, 1); oi = __shfl_xor(bi0, 1);
    bs0 = fmaxf(fmaxf(bs0, os), fminf(bv0, ov));
    bi0 = (ov > bv0) ? oi : bi0;
    bv0 = fmaxf(bv0, ov);
    ov = __shfl_xor(bv1, 1); os = __shfl_xor(bs1, 1); oi = __shfl_xor(bi1, 1);
    bs1 = fmaxf(fmaxf(bs1, os), fminf(bv1, ov));
    bi1 = (ov > bv1) ? oi : bi1;
    bv1 = fmaxf(bv1, ov);
  }
  if ((cg & 1) == 0) {
    int rr_ = cg >> 1;
    sb[(tg * 2 + 0) * 4 + rr_] = bi0;
    sb[(tg * 2 + 1) * 4 + rr_] = bi1;
    if (bv0 - bs0 < THRESH) {
      int ix = atomicAdd(cnt, 1);
      if (ix < MAXFLAG) flaglist[ix] = (b << 14) | ((tok0 + tg * 2 + 0) << 2) | rr_;
    }
    if (bv1 - bs1 < THRESH) {
      int ix = atomicAdd(cnt, 1);
      if (ix < MAXFLAG) flaglist[ix] = (b << 14) | ((tok0 + tg * 2 + 1) << 2) | rr_;
    }
  }
  __syncthreads();
  if (t < 64)
    ((int4*)bucket)[(size_t)b * L_ + tok0 + t] = ((int4*)sb)[t];

  // ---- emit normalized bf16 Q rows + scale (exact same reduction order) ----
  if (t < 128) {
    int row = t >> 1, half = t & 1;
    const float* qp = qs + row * 68 + half * 32;
    float v[32];
    float ss = 0.f;
    #pragma unroll
    for (int u = 0; u < 8; ++u) {
      float4 x = *(const float4*)(qp + u * 4);
      v[u*4+0] = x.x; v[u*4+1] = x.y; v[u*4+2] = x.z; v[u*4+3] = x.w;
      ss += x.x*x.x + x.y*x.y + x.z*x.z + x.w*x.w;
    }
    ss += __shfl_xor(ss, 1);
    float inv = 1.0f / fmaxf(sqrtf(ss), 1e-12f);
    unsigned short* qn = Qn + ((size_t)b * L_ + tok0 + row) * 64 + half * 32;
    #pragma unroll
    for (int u = 0; u < 4; ++u) {
      uint4 pk;
      pk.x = cvtpk(v[u*8+0] * inv, v[u*8+1] * inv);
      pk.y = cvtpk(v[u*8+2] * inv, v[u*8+3] * inv);
      pk.z = cvtpk(v[u*8+4] * inv, v[u*8+5] * inv);
      pk.w = cvtpk(v[u*8+6] * inv, v[u*8+7] * inv);
      ((uint4*)qn)[u] = pk;
    }
    if (half == 0)
      qscale[(size_t)b * L_ + tok0 + row] = 0.18033688f / inv;  // 0.125*log2e*|q|
  }

  // ---- convert this block's V rows to bf16 (adjacent-pair cvtpk) ----
  {
    int row = t >> 2, qd = t & 3;
    const float* vr = value + ((size_t)b * L_ + tok0 + row) * DK_ + qd * 16;
    float4 x0 = ((const float4*)vr)[0], x1 = ((const float4*)vr)[1],
           x2 = ((const float4*)vr)[2], x3 = ((const float4*)vr)[3];
    uint4 p0, p1;
    p0.x = cvtpk(x0.x, x0.y); p0.y = cvtpk(x0.z, x0.w);
    p0.z = cvtpk(x1.x, x1.y); p0.w = cvtpk(x1.z, x1.w);
    p1.x = cvtpk(x2.x, x2.y); p1.y = cvtpk(x2.z, x2.w);
    p1.z = cvtpk(x3.x, x3.y); p1.w = cvtpk(x3.z, x3.w);
    unsigned short* out = Vb + ((size_t)b * L_ + tok0 + row) * 64 + qd * 16;
    ((uint4*)out)[0] = p0;
    ((uint4*)out)[1] = p1;
  }
}

// ---- Kernel 1.5: exact fp64 fixup for margin-flagged decisions --------------
// One wave per flagged (b,l,r); same d-ascending fp64 chains as the historical
// fp64 hash -> bit-identical decisions.
__global__ __launch_bounds__(64) void fixup_kernel(
    const float* __restrict__ query, const float* __restrict__ rm,
    const int* __restrict__ flaglist, const int* __restrict__ cnt,
    int* __restrict__ bucket) {
  int nfl = *cnt;
  if (nfl > MAXFLAG) nfl = MAXFLAG;
  int lane = threadIdx.x;
  for (int i = blockIdx.x; i < nfl; i += gridDim.x) {
    int code = flaglist[i];
    int r = code & 3, l = (code >> 2) & 4095, b = code >> 14;
    int col = r * 32 + (lane & 31);
    const float* qrow = query + ((size_t)b * L_ + l) * DK_;
    const float* rmc = rm + (size_t)b * (DK_ * 128) + col;
    double acc = 0.0, ss = 0.0;
    for (int d = 0; d < DK_; ++d) {
      double qv = (double)qrow[d];
      double rv = (double)rmc[d * 128];
      acc += qv * rv;
      ss += rv * rv;
    }
    double sinv = 1.0 / sqrt(ss);
    double v = acc * sinv;
    double bv = (lane < 32) ? v : -v;
    int bi = lane;
    #pragma unroll
    for (int msk = 1; msk < 64; msk <<= 1) {
      double ov = __shfl_xor(bv, msk);
      int oi = __shfl_xor(bi, msk);
      if (ov > bv || (ov == bv && oi < bi)) { bv = ov; bi = oi; }
    }
    if (lane == 0) bucket[((size_t)b * L_ + l) * 4 + r] = bi;
  }
}

// ------- Kernel 2: 16-wave two-level stable counting sort per (b, r) --------
__global__ __launch_bounds__(1024) void sort_kernel(
    const int* __restrict__ bucket, int* __restrict__ sorted_pos,
    unsigned char* __restrict__ cpack) {
  int b = blockIdx.x >> 2;
  int r = blockIdx.x & 3;
  __shared__ int hist[64 * 65];   // [chunk][bin], stride 65
  __shared__ int off[64];
  int t = threadIdx.x, lane = t & 63, w = t >> 6;
  unsigned long long ltmask = (1ull << lane) - 1ull;
  const int* bb = bucket + (size_t)b * L_ * 4 + r;

  int binv[4], rank[4];
  #pragma unroll
  for (int u = 0; u < 4; ++u)
    binv[u] = bb[(size_t)((w * 4 + u) * 64 + lane) * 4];

  for (int idx = t; idx < 64 * 65; idx += 1024) hist[idx] = 0;
  __syncthreads();

  #pragma unroll
  for (int u = 0; u < 4; ++u) {
    int bin = binv[u];
    unsigned long long m = ~0ull;
    #pragma unroll
    for (int k = 0; k < 6; ++k) {
      unsigned long long bal = __ballot((bin >> k) & 1);
      m &= ((bin >> k) & 1) ? bal : ~bal;
    }
    rank[u] = (int)__popcll(m & ltmask);
    if (rank[u] == 0) hist[(w * 4 + u) * 65 + bin] = (int)__popcll(m);
  }
  __syncthreads();

  if (w == 0) {
    int run = 0;
    for (int g = 0; g < 64; ++g) {
      int v = hist[g * 65 + lane];
      hist[g * 65 + lane] = run;
      run += v;
    }
    int inc = run;
    #pragma unroll
    for (int d = 1; d < 64; d <<= 1) {
      int y = __shfl_up(inc, d, 64);
      if (lane >= d) inc += y;
    }
    off[lane] = inc - run;
  }
  __syncthreads();

  int* sp = sorted_pos + ((size_t)b * R_ + r) * L_;
  unsigned char* cp = cpack + (size_t)b * L_ * 4 + r;
  #pragma unroll
  for (int u = 0; u < 4; ++u) {
    int g = w * 4 + u;
    int bin = binv[u];
    int slot = off[bin] + hist[g * 65 + bin] + rank[u];
    sp[slot] = g * 64 + lane;
    cp[(size_t)(g * 64 + lane) * 4] = (unsigned char)(slot >> 6);
  }
}

// ---------------- Kernel 3: per-chunk attention (bf16 MFMA, R11 form) --------
__global__ __launch_bounds__(256) void attn_kernel(
    const unsigned short* __restrict__ Qn, const unsigned short* __restrict__ Vb,
    const float* __restrict__ qscale,
    const int* __restrict__ sorted_pos, const int* __restrict__ bucket,
    const int* __restrict__ cpack,
    unsigned short* __restrict__ att, float* __restrict__ lse_s) {
  int wg = (int)blockIdx.x;
  wg = (wg & 7) * (B_ * R_ * NB_ / 8) + (wg >> 3);   // XCD-contiguous swizzle
  int n = wg & 63;
  int r = (wg >> 6) & 3;
  int b = wg >> 8;
  int br = b * R_ + r;
  int nprev = (n + 63) & 63;

  __shared__ __align__(16) short bufK[128 * 64];   // K_norm bf16; reused as VT[64][128]
  __shared__ int skpos[128];
  __shared__ int skcode[128];                      // (bucket<<12) | pos
  __shared__ int sck[128];                         // packed chunk ids (4x8b)

  int t = threadIdx.x;
  if (t < 128) {
    int chunk = (t < 64) ? nprev : n;
    int pos = sorted_pos[(size_t)br * L_ + chunk * 64 + (t & 63)];
    skpos[t] = pos;
    skcode[t] = (bucket[((size_t)b * L_ + pos) * 4 + r] << 12) | pos;
    sck[t] = ((const int*)cpack)[(size_t)b * L_ + pos];
  }
  __syncthreads();

  int l = t & 63, w = t >> 6;
  int g = l >> 4, c = l & 15;
  int qi = w * 16 + c;

  // ---- K staging from Qn (bf16, swizzled LDS image) ----
  {
    int j = t >> 1, half = t & 1;
    const uint4* src = (const uint4*)(Qn + ((size_t)b * L_ + skpos[j]) * 64 + half * 32);
    short* krow = bufK + j * 64;
    int sz = swz(j);
    #pragma unroll
    for (int u = 0; u < 4; ++u)
      *(uint4*)(krow + (((half * 4 + u) ^ sz) << 3)) = src[u];
  }
  int qcode = skcode[64 + qi];
  int qpos = qcode & 4095;
  float csc = qscale[(size_t)b * L_ + qpos];   // issued early; used post-QK
  __syncthreads();

  // ---- QK^T via MFMA, SWAPPED: D = K_frag · Q_frag = S^T ----
  f32x4 acc[8];
  #pragma unroll
  for (int tt = 0; tt < 8; ++tt) acc[tt] = (f32x4){0.f, 0.f, 0.f, 0.f};
  {
    int qrow = 64 + qi;
    const short* qp_ = bufK + qrow * 64;
    bf16x8 q0 = *(const bf16x8*)(qp_ + (((g) ^ swz(qrow)) << 3));
    bf16x8 q1 = *(const bf16x8*)(qp_ + (((4 + g) ^ swz(qrow)) << 3));
    #pragma unroll
    for (int tt = 0; tt < 8; ++tt) {
      int krow = tt * 16 + c;
      const short* kp_ = bufK + krow * 64;
      bf16x8 k0 = *(const bf16x8*)(kp_ + (((g) ^ swz(krow)) << 3));
      bf16x8 k1 = *(const bf16x8*)(kp_ + (((4 + g) ^ swz(krow)) << 3));
      acc[tt] = __builtin_amdgcn_mfma_f32_16x16x32_bf16(k0, q0, acc[tt], 0, 0, 0);
      acc[tt] = __builtin_amdgcn_mfma_f32_16x16x32_bf16(k1, q1, acc[tt], 0, 0, 0);
    }
  }
  __syncthreads();   // all waves done reading bufK (VT will overwrite)

  // ---- issue V gathers early (bf16); consumed after softmax ----
  int pi = t >> 2, qd = t & 3;
  const uint4* vr0 = (const uint4*)(Vb + ((size_t)b * L_ + skpos[2 * pi]) * 64 + qd * 16);
  const uint4* vr1 = (const uint4*)(Vb + ((size_t)b * L_ + skpos[2 * pi + 1]) * 64 + qd * 16);
  uint4 A0 = vr0[0], A1 = vr0[1];
  uint4 B0 = vr1[0], B1 = vr1[1];

  // ---- masks + lane-local softmax (exp2 domain) ----
  unsigned aq = (unsigned)sck[64 + qi] | 0x40404040u;

  float m = -1e30f;
  #pragma unroll
  for (int tt = 0; tt < 8; ++tt) {
    int4 kc = *(const int4*)(skcode + tt * 16 + g * 4);
    #pragma unroll
    for (int j = 0; j < 4; ++j) {
      int kcode = (j == 0) ? kc.x : (j == 1) ? kc.y : (j == 2) ? kc.z : kc.w;
      float s = acc[tt][j] * csc;
      unsigned x = (unsigned)(qcode ^ kcode);
      s = ((qcode < kcode) || (x >= 4096u)) ? -1e9f : s;
      s = (x == 0u) ? -144269.5f : s;   // -1e5 * log2e
      acc[tt][j] = s;
      m = fmaxf(m, s);
    }
  }
  m = fmaxf(m, __shfl_xor(m, 16));
  m = fmaxf(m, __shfl_xor(m, 32));
  float sum = 0.f;
  #pragma unroll
  for (int tt = 0; tt < 8; ++tt) {
    #pragma unroll
    for (int j = 0; j < 4; ++j) {
      float e = exp2f(acc[tt][j] - m);
      acc[tt][j] = e;
      sum += e;
    }
  }
  sum += __shfl_xor(sum, 16);
  sum += __shfl_xor(sum, 32);
  float lse = 0.69314718f * (m + __log2f(sum));
  float isum = 1.0f / sum;
  if (l < 16) lse_s[(size_t)br * L_ + qpos] = lse;

  // ---- dup-count (SWAR) -> final P in registers ----
  #pragma unroll
  for (int tt = 0; tt < 8; ++tt) {
    int4 c4v = *(const int4*)(sck + tt * 16 + g * 4);
    #pragma unroll
    for (int j = 0; j < 4; ++j) {
      int ckv = (j == 0) ? c4v.x : (j == 1) ? c4v.y : (j == 2) ? c4v.z : c4v.w;
      unsigned e = (aq - (unsigned)ckv) & 0x3E3E3E3Eu;
      unsigned y = (e - 0x01010101u) & ~e & 0x80808080u;
      float cntf = (float)__popc(y);
      acc[tt][j] = acc[tt][j] * isum * __builtin_amdgcn_rcpf(cntf);
    }
  }

  // ---- P -> bf16 pairs in registers ----
  unsigned pk01[8], pk23[8];
  #pragma unroll
  for (int tt = 0; tt < 8; ++tt) {
    pk01[tt] = cvtpk(acc[tt][0], acc[tt][1]);
    pk23[tt] = cvtpk(acc[tt][2], acc[tt][3]);
  }

  // ---- VT staging into freed bufK (transpose from bf16 regs) ----
  short* VT = bufK;
  {
    unsigned Aw[8] = {A0.x, A0.y, A0.z, A0.w, A1.x, A1.y, A1.z, A1.w};
    unsigned Bw[8] = {B0.x, B0.y, B0.z, B0.w, B1.x, B1.y, B1.z, B1.w};
    int k0 = 2 * pi;
    #pragma unroll
    for (int i = 0; i < 8; ++i) {
      unsigned lo = (Aw[i] & 0xffffu) | (Bw[i] << 16);
      unsigned hi = (Aw[i] >> 16) | (Bw[i] & 0xffff0000u);
      int dl = qd * 16 + 2 * i, dh = dl + 1;
      *(unsigned*)(VT + dl * 128 + (((k0 >> 3) ^ swz(dl)) << 3) + (k0 & 7)) = lo;
      *(unsigned*)(VT + dh * 128 + (((k0 >> 3) ^ swz(dh)) << 3) + (k0 & 7)) = hi;
    }
  }
  __syncthreads();

  // ---- PV via MFMA: O^T[d][q] = sum_k VT[d][k] * P^T[k][q] ----
  f32x4 o[4];
  #pragma unroll
  for (int nt = 0; nt < 4; ++nt) o[nt] = (f32x4){0.f, 0.f, 0.f, 0.f};
  {
    int src  = (g & 1) * 32 + c;
    int srcB = src + 16;
    bool sel = (l >= 32);
    #pragma unroll
    for (int ks = 0; ks < 4; ++ks) {
      unsigned xA = __shfl(pk01[2 * ks], src),  yA = __shfl(pk01[2 * ks + 1], src);
      unsigned xB = __shfl(pk23[2 * ks], src),  yB = __shfl(pk23[2 * ks + 1], src);
      unsigned xC = __shfl(pk01[2 * ks], srcB), yC = __shfl(pk01[2 * ks + 1], srcB);
      unsigned xD = __shfl(pk23[2 * ks], srcB), yD = __shfl(pk23[2 * ks + 1], srcB);
      union { uint4 u; bf16x8 v; } bp;
      bp.u.x = sel ? yA : xA;
      bp.u.y = sel ? yB : xB;
      bp.u.z = sel ? yC : xC;
      bp.u.w = sel ? yD : xD;
      #pragma unroll
      for (int nt = 0; nt < 4; ++nt) {
        int vrow = nt * 16 + c;
        bf16x8 av = *(const bf16x8*)(VT + vrow * 128 + (((ks * 4 + g) ^ swz(vrow)) << 3));
        o[nt] = __builtin_amdgcn_mfma_f32_16x16x32_bf16(av, bp.v, o[nt], 0, 0, 0);
      }
    }
  }

  // ---- scatter att rows (bf16, 8B stores): lane owns one q-row ----
  {
    unsigned short* arow = att + ((size_t)br * L_ + qpos) * DK_;
    #pragma unroll
    for (int nt = 0; nt < 4; ++nt) {
      unsigned p0 = cvtpk(o[nt][0], o[nt][1]);
      unsigned p1 = cvtpk(o[nt][2], o[nt][3]);
      *(uint2*)(arow + nt * 16 + g * 4) = make_uint2(p0, p1);
    }
  }
}

// ---------------- Kernel 4: softmax reduction over L of lse ------------------
__global__ __launch_bounds__(256) void lsered_kernel(
    const float* __restrict__ lse_s, float* __restrict__ wred) {
  int br = blockIdx.x;
  const float* row = lse_s + (size_t)br * L_;
  __shared__ float red[4];
  int t = threadIdx.x;
  float m = -1e30f;
  for (int p = t; p < L_; p += 256) m = fmaxf(m, row[p]);
  #pragma unroll
  for (int mask = 1; mask < 64; mask <<= 1) m = fmaxf(m, __shfl_xor(m, mask, 64));
  if ((t & 63) == 0) red[t >> 6] = m;
  __syncthreads();
  m = fmaxf(fmaxf(red[0], red[1]), fmaxf(red[2], red[3]));
  __syncthreads();
  float sum = 0.f;
  for (int p = t; p < L_; p += 256) sum += __expf(row[p] - m);
  #pragma unroll
  for (int mask = 1; mask < 64; mask <<= 1) sum += __shfl_xor(sum, mask, 64);
  if ((t & 63) == 0) red[t >> 6] = sum;
  __syncthreads();
  if (t == 0) {
    wred[br * 2] = m;
    wred[br * 2 + 1] = red[0] + red[1] + red[2] + red[3];
  }
}

// ---------------- Kernel 5: weighted combine over rounds ---------------------
__global__ __launch_bounds__(256) void combine_kernel(
    const unsigned short* __restrict__ att, const float* __restrict__ lse_s,
    const float* __restrict__ wred, float* __restrict__ out) {
  int idx = blockIdx.x * 256 + threadIdx.x;
  int dq = idx & 3;
  int l = (idx >> 2) & (L_ - 1);
  int b = idx >> 14;
  float wv[4];
  #pragma unroll
  for (int r = 0; r < R_; ++r) {
    float m = wred[(b * R_ + r) * 2];
    float sinv = 1.0f / wred[(b * R_ + r) * 2 + 1];
    wv[r] = __expf(lse_s[((size_t)b * R_ + r) * L_ + l] - m) * sinv;
  }
  #pragma unroll
  for (int u = 0; u < 4; ++u) {
    int d4 = dq * 4 + u;
    float4 o = make_float4(0.f, 0.f, 0.f, 0.f);
    #pragma unroll
    for (int r = 0; r < R_; ++r) {
      ushort4 a = *(const ushort4*)(att + ((((size_t)b * R_ + r) * L_ + l) * 16 + d4) * 4);
      o.x += wv[r] * bf2f(a.x); o.y += wv[r] * bf2f(a.y);
      o.z += wv[r] * bf2f(a.z); o.w += wv[r] * bf2f(a.w);
    }
    ((float4*)out)[((size_t)b * L_ + l) * 16 + d4] = o;
  }
}

extern "C" void kernel_launch(void* const* d_in, const int* in_sizes, int n_in,
                              void* d_out, int out_size, void* d_ws, size_t ws_size,
                              hipStream_t stream) {
  const float* query = (const float*)d_in[0];
  const float* value = (const float*)d_in[1];
  const float* rm    = (const float*)d_in[2];
  (void)in_sizes; (void)n_in; (void)out_size; (void)ws_size;

  char* ws = (char*)d_ws;
  const size_t ATT_BYTES = (size_t)B_ * R_ * L_ * DK_ * 2;  // 32 MiB (bf16)
  const size_t MB = 1048576;
  unsigned short* att        = (unsigned short*)ws;
  int*            bucket     = (int*)(ws + ATT_BYTES);
  int*            sorted_pos = (int*)(ws + ATT_BYTES + 1 * MB);
  unsigned char*  cpack      = (unsigned char*)(ws + ATT_BYTES + 2 * MB);
  float*          lse_s      = (float*)(ws + ATT_BYTES + 3 * MB);
  float*          wred       = (float*)(ws + ATT_BYTES + 4 * MB);
  float*          qscale     = (float*)(ws + ATT_BYTES + 6 * MB);
  unsigned short* Qn         = (unsigned short*)(ws + ATT_BYTES + 8 * MB);
  unsigned short* Vb         = (unsigned short*)(ws + ATT_BYTES + 16 * MB);
  int*            cnt        = (int*)(ws + ATT_BYTES + 24 * MB);
  int*            flaglist   = (int*)(ws + ATT_BYTES + 25 * MB);
  float* out = (float*)d_out;

  zc_kernel<<<1, 1, 0, stream>>>(cnt);
  hash_kernel<<<B_ * 64, 256, 0, stream>>>(query, value, rm, bucket, Qn, qscale,
                                           Vb, cnt, flaglist);
  fixup_kernel<<<4096, 64, 0, stream>>>(query, rm, flaglist, cnt, bucket);
  sort_kernel<<<B_ * R_, 1024, 0, stream>>>(bucket, sorted_pos, cpack);
  attn_kernel<<<B_ * R_ * NB_, 256, 0, stream>>>(Qn, Vb, qscale, sorted_pos,
                                                 bucket, (const int*)cpack,
                                                 att, lse_s);
  lsered_kernel<<<B_ * R_, 256, 0, stream>>>(lse_s, wred);
  combine_kernel<<<(B_ * L_ * 4) / 256, 256, 0, stream>>>(att, lse_s, wred, out);
}

// Round 18
// 122.472 us; speedup vs baseline: 8.6885x; 1.2481x over previous
//
#include <hip/hip_runtime.h>

#define B_ 16
#define L_ 4096
#define DK_ 64
#define R_ 4
#define NB_ 64
#define BL_ 64
#define MAXFLAG 65536
#define THRESH 4e-3f

typedef __attribute__((ext_vector_type(8))) short bf16x8;
typedef __attribute__((ext_vector_type(4))) float f32x4;

__device__ __forceinline__ float bf2f(unsigned short u) {
  return __uint_as_float(((unsigned)u) << 16);
}
// HW packed f32->bf16 (RNE) — 1 inst per 2 values
__device__ __forceinline__ unsigned cvtpk(float lo, float hi) {
  unsigned r;
  asm("v_cvt_pk_bf16_f32 %0, %1, %2" : "=v"(r) : "v"(lo), "v"(hi));
  return r;
}
__device__ __forceinline__ int swz(int row) { return (row & 7) ^ ((row >> 3) & 7); }

// ---- Kernel 0: zero the flag counter ----------------------------------------
__global__ void zc_kernel(int* cnt) { *cnt = 0; }

// ---- Kernel 1: LSH hashing — fp32 fast path, ROLLED outer loops -------------
// #pragma unroll 1 on the d4/ssp loops keeps live ranges bounded (R16/R17
// spilled at VGPR=256 from full unroll + load hoisting). Decisions with
// top-2 margin < THRESH go to flaglist for exact fp64 fixup.
__global__ __launch_bounds__(256) void hash_kernel(
    const float* __restrict__ query, const float* __restrict__ value,
    const float* __restrict__ rm, int* __restrict__ bucket,
    unsigned short* __restrict__ Qn, float* __restrict__ qscale,
    unsigned short* __restrict__ Vb,
    int* __restrict__ cnt, int* __restrict__ flaglist) {
  __shared__ float qs[64 * 68];      // q[tok][d], stride 68   (17408B)
  __shared__ float rs[32 * 160];     // rm half-d [32][cg*20]  (20480B)
  __shared__ float ssinf[128];       // (512B)
  __shared__ int sb[64 * 4];         // (1024B)

  int b = blockIdx.x >> 6;
  int tok0 = (blockIdx.x & 63) << 6;   // 64 tokens per block
  int t = threadIdx.x;

  {  // stage q: 64 tok x 16 float4
    const float4* qg = (const float4*)(query + ((size_t)b * L_ + tok0) * DK_);
    #pragma unroll
    for (int u = 0; u < 4; ++u) {
      int i = t + u * 256;
      int tokl = i >> 4, c4 = i & 15;
      *(float4*)(qs + tokl * 68 + c4 * 4) = qg[i];
    }
  }
  {  // stage rm rows d = 0..31 into padded-cg layout
    const float4* rg = (const float4*)(rm + (size_t)b * (DK_ * 128));
    #pragma unroll
    for (int u = 0; u < 4; ++u) {
      int i = t + u * 256;
      int d = i >> 5, c4 = i & 31;
      int cg2 = c4 >> 2, j4 = c4 & 3;
      *(float4*)(rs + d * 160 + cg2 * 20 + j4 * 4) = rg[i];
    }
  }
  __syncthreads();

  // ssin partial over d = 0..31 (fp32, rolled)
  float ssp = 0.f;
  if (t < 128) {
    const float* colp = rs + (t >> 4) * 20 + (t & 15);
    #pragma unroll 1
    for (int d = 0; d < 32; ++d) {
      float v = colp[d * 160];
      ssp += v * v;
    }
  }

  int cg = t & 7;
  int tg = t >> 3;
  float acc0[16], acc1[16];
  #pragma unroll
  for (int j = 0; j < 16; ++j) { acc0[j] = 0.f; acc1[j] = 0.f; }

  const float* q0 = qs + (tg * 2 + 0) * 68;
  const float* q1 = qs + (tg * 2 + 1) * 68;
  const float* rp = rs + cg * 20;

  // ---- acc part 1: d = 0..31 (rolled outer loop) ----
  #pragma unroll 1
  for (int d4 = 0; d4 < 8; ++d4) {
    float4 qa4 = *(const float4*)(q0 + d4 * 4);
    float4 qb4 = *(const float4*)(q1 + d4 * 4);
    #pragma unroll
    for (int sub = 0; sub < 4; ++sub) {
      float qa = (sub == 0) ? qa4.x : (sub == 1) ? qa4.y : (sub == 2) ? qa4.z : qa4.w;
      float qb = (sub == 0) ? qb4.x : (sub == 1) ? qb4.y : (sub == 2) ? qb4.z : qb4.w;
      const float* rr = rp + (d4 * 4 + sub) * 160;
      #pragma unroll
      for (int j4 = 0; j4 < 4; ++j4) {
        float4 rv = *(const float4*)(rr + j4 * 4);
        acc0[j4 * 4 + 0] += qa * rv.x; acc0[j4 * 4 + 1] += qa * rv.y;
        acc0[j4 * 4 + 2] += qa * rv.z; acc0[j4 * 4 + 3] += qa * rv.w;
        acc1[j4 * 4 + 0] += qb * rv.x; acc1[j4 * 4 + 1] += qb * rv.y;
        acc1[j4 * 4 + 2] += qb * rv.z; acc1[j4 * 4 + 3] += qb * rv.w;
      }
    }
  }
  __syncthreads();   // everyone done reading rs half 1

  {  // stage rm rows d = 32..63
    const float4* rg = (const float4*)(rm + (size_t)b * (DK_ * 128)) + 1024;
    #pragma unroll
    for (int u = 0; u < 4; ++u) {
      int i = t + u * 256;
      int d = i >> 5, c4 = i & 31;
      int cg2 = c4 >> 2, j4 = c4 & 3;
      *(float4*)(rs + d * 160 + cg2 * 20 + j4 * 4) = rg[i];
    }
  }
  __syncthreads();

  // ssin finish over d = 32..63 (rolled)
  if (t < 128) {
    const float* colp = rs + (t >> 4) * 20 + (t & 15);
    #pragma unroll 1
    for (int d = 0; d < 32; ++d) {
      float v = colp[d * 160];
      ssp += v * v;
    }
    ssinf[t] = 1.0f / sqrtf(ssp);
  }

  // ---- acc part 2: d = 32..63 (rolled outer loop) ----
  #pragma unroll 1
  for (int d4 = 8; d4 < 16; ++d4) {
    float4 qa4 = *(const float4*)(q0 + d4 * 4);
    float4 qb4 = *(const float4*)(q1 + d4 * 4);
    #pragma unroll
    for (int sub = 0; sub < 4; ++sub) {
      float qa = (sub == 0) ? qa4.x : (sub == 1) ? qa4.y : (sub == 2) ? qa4.z : qa4.w;
      float qb = (sub == 0) ? qb4.x : (sub == 1) ? qb4.y : (sub == 2) ? qb4.z : qb4.w;
      const float* rr = rp + ((d4 - 8) * 4 + sub) * 160;
      #pragma unroll
      for (int j4 = 0; j4 < 4; ++j4) {
        float4 rv = *(const float4*)(rr + j4 * 4);
        acc0[j4 * 4 + 0] += qa * rv.x; acc0[j4 * 4 + 1] += qa * rv.y;
        acc0[j4 * 4 + 2] += qa * rv.z; acc0[j4 * 4 + 3] += qa * rv.w;
        acc1[j4 * 4 + 0] += qb * rv.x; acc1[j4 * 4 + 1] += qb * rv.y;
        acc1[j4 * 4 + 2] += qb * rv.z; acc1[j4 * 4 + 3] += qb * rv.w;
      }
    }
  }
  __syncthreads();   // ssinf final visible to all

  // ---- branchless top-2 argmax (fp32) ----
  float bv0 = -1e30f, bs0 = -1e30f;
  float bv1 = -1e30f, bs1 = -1e30f;
  int bi0 = 0, bi1 = 0;
  int nbase = (cg & 1) * 16;
  #pragma unroll
  for (int j = 0; j < 16; ++j) {
    int col = cg * 16 + j;
    float sv = ssinf[col];
    int n = nbase + j;
    float v0 = acc0[j] * sv;
    float v1 = acc1[j] * sv;
    bs0 = fmaxf(bs0, fminf(bv0, v0));
    bi0 = (v0 > bv0) ? n : bi0;
    bv0 = fmaxf(bv0, v0);
    float w0 = -v0;
    bs0 = fmaxf(bs0, fminf(bv0, w0));
    bi0 = (w0 > bv0) ? (n + 32) : bi0;
    bv0 = fmaxf(bv0, w0);
    bs1 = fmaxf(bs1, fminf(bv1, v1));
    bi1 = (v1 > bv1) ? n : bi1;
    bv1 = fmaxf(bv1, v1);
    float w1 = -v1;
    bs1 = fmaxf(bs1, fminf(bv1, w1));
    bi1 = (w1 > bv1) ? (n + 32) : bi1;
    bv1 = fmaxf(bv1, w1);
  }
  {  // merge the two half-round threads (cg even/odd), branchless
    float ov, os; int oi;
    ov = __shfl_xor(bv0, 1); os = __shfl_xor(bs0, 1); oi = __shfl_xor(bi0, 1);
    bs0 = fmaxf(fmaxf(bs0, os), fminf(bv0, ov));
    bi0 = (ov > bv0) ? oi : bi0;
    bv0 = fmaxf(bv0, ov);
    ov = __shfl_xor(bv1, 1); os = __shfl_xor(bs1, 1); oi = __shfl_xor(bi1, 1);
    bs1 = fmaxf(fmaxf(bs1, os), fminf(bv1, ov));
    bi1 = (ov > bv1) ? oi : bi1;
    bv1 = fmaxf(bv1, ov);
  }
  if ((cg & 1) == 0) {
    int rr_ = cg >> 1;
    sb[(tg * 2 + 0) * 4 + rr_] = bi0;
    sb[(tg * 2 + 1) * 4 + rr_] = bi1;
    if (bv0 - bs0 < THRESH) {
      int ix = atomicAdd(cnt, 1);
      if (ix < MAXFLAG) flaglist[ix] = (b << 14) | ((tok0 + tg * 2 + 0) << 2) | rr_;
    }
    if (bv1 - bs1 < THRESH) {
      int ix = atomicAdd(cnt, 1);
      if (ix < MAXFLAG) flaglist[ix] = (b << 14) | ((tok0 + tg * 2 + 1) << 2) | rr_;
    }
  }
  __syncthreads();
  if (t < 64)
    ((int4*)bucket)[(size_t)b * L_ + tok0 + t] = ((int4*)sb)[t];

  // ---- emit normalized bf16 Q rows + scale (exact same reduction order) ----
  if (t < 128) {
    int row = t >> 1, half = t & 1;
    const float* qp = qs + row * 68 + half * 32;
    float v[32];
    float ss = 0.f;
    #pragma unroll
    for (int u = 0; u < 8; ++u) {
      float4 x = *(const float4*)(qp + u * 4);
      v[u*4+0] = x.x; v[u*4+1] = x.y; v[u*4+2] = x.z; v[u*4+3] = x.w;
      ss += x.x*x.x + x.y*x.y + x.z*x.z + x.w*x.w;
    }
    ss += __shfl_xor(ss, 1);
    float inv = 1.0f / fmaxf(sqrtf(ss), 1e-12f);
    unsigned short* qn = Qn + ((size_t)b * L_ + tok0 + row) * 64 + half * 32;
    #pragma unroll
    for (int u = 0; u < 4; ++u) {
      uint4 pk;
      pk.x = cvtpk(v[u*8+0] * inv, v[u*8+1] * inv);
      pk.y = cvtpk(v[u*8+2] * inv, v[u*8+3] * inv);
      pk.z = cvtpk(v[u*8+4] * inv, v[u*8+5] * inv);
      pk.w = cvtpk(v[u*8+6] * inv, v[u*8+7] * inv);
      ((uint4*)qn)[u] = pk;
    }
    if (half == 0)
      qscale[(size_t)b * L_ + tok0 + row] = 0.18033688f / inv;  // 0.125*log2e*|q|
  }

  // ---- convert this block's V rows to bf16 (adjacent-pair cvtpk) ----
  {
    int row = t >> 2, qd = t & 3;
    const float* vr = value + ((size_t)b * L_ + tok0 + row) * DK_ + qd * 16;
    float4 x0 = ((const float4*)vr)[0], x1 = ((const float4*)vr)[1],
           x2 = ((const float4*)vr)[2], x3 = ((const float4*)vr)[3];
    uint4 p0, p1;
    p0.x = cvtpk(x0.x, x0.y); p0.y = cvtpk(x0.z, x0.w);
    p0.z = cvtpk(x1.x, x1.y); p0.w = cvtpk(x1.z, x1.w);
    p1.x = cvtpk(x2.x, x2.y); p1.y = cvtpk(x2.z, x2.w);
    p1.z = cvtpk(x3.x, x3.y); p1.w = cvtpk(x3.z, x3.w);
    unsigned short* out = Vb + ((size_t)b * L_ + tok0 + row) * 64 + qd * 16;
    ((uint4*)out)[0] = p0;
    ((uint4*)out)[1] = p1;
  }
}

// ---- Kernel 1.5: exact fp64 fixup for margin-flagged decisions --------------
__global__ __launch_bounds__(64) void fixup_kernel(
    const float* __restrict__ query, const float* __restrict__ rm,
    const int* __restrict__ flaglist, const int* __restrict__ cnt,
    int* __restrict__ bucket) {
  int nfl = *cnt;
  if (nfl > MAXFLAG) nfl = MAXFLAG;
  int lane = threadIdx.x;
  for (int i = blockIdx.x; i < nfl; i += gridDim.x) {
    int code = flaglist[i];
    int r = code & 3, l = (code >> 2) & 4095, b = code >> 14;
    int col = r * 32 + (lane & 31);
    const float* qrow = query + ((size_t)b * L_ + l) * DK_;
    const float* rmc = rm + (size_t)b * (DK_ * 128) + col;
    double acc = 0.0, ss = 0.0;
    for (int d = 0; d < DK_; ++d) {
      double qv = (double)qrow[d];
      double rv = (double)rmc[d * 128];
      acc += qv * rv;
      ss += rv * rv;
    }
    double sinv = 1.0 / sqrt(ss);
    double v = acc * sinv;
    double bv = (lane < 32) ? v : -v;
    int bi = lane;
    #pragma unroll
    for (int msk = 1; msk < 64; msk <<= 1) {
      double ov = __shfl_xor(bv, msk);
      int oi = __shfl_xor(bi, msk);
      if (ov > bv || (ov == bv && oi < bi)) { bv = ov; bi = oi; }
    }
    if (lane == 0) bucket[((size_t)b * L_ + l) * 4 + r] = bi;
  }
}

// ------- Kernel 2: 16-wave two-level stable counting sort per (b, r) --------
__global__ __launch_bounds__(1024) void sort_kernel(
    const int* __restrict__ bucket, int* __restrict__ sorted_pos,
    unsigned char* __restrict__ cpack) {
  int b = blockIdx.x >> 2;
  int r = blockIdx.x & 3;
  __shared__ int hist[64 * 65];   // [chunk][bin], stride 65
  __shared__ int off[64];
  int t = threadIdx.x, lane = t & 63, w = t >> 6;
  unsigned long long ltmask = (1ull << lane) - 1ull;
  const int* bb = bucket + (size_t)b * L_ * 4 + r;

  int binv[4], rank[4];
  #pragma unroll
  for (int u = 0; u < 4; ++u)
    binv[u] = bb[(size_t)((w * 4 + u) * 64 + lane) * 4];

  for (int idx = t; idx < 64 * 65; idx += 1024) hist[idx] = 0;
  __syncthreads();

  #pragma unroll
  for (int u = 0; u < 4; ++u) {
    int bin = binv[u];
    unsigned long long m = ~0ull;
    #pragma unroll
    for (int k = 0; k < 6; ++k) {
      unsigned long long bal = __ballot((bin >> k) & 1);
      m &= ((bin >> k) & 1) ? bal : ~bal;
    }
    rank[u] = (int)__popcll(m & ltmask);
    if (rank[u] == 0) hist[(w * 4 + u) * 65 + bin] = (int)__popcll(m);
  }
  __syncthreads();

  if (w == 0) {
    int run = 0;
    for (int g = 0; g < 64; ++g) {
      int v = hist[g * 65 + lane];
      hist[g * 65 + lane] = run;
      run += v;
    }
    int inc = run;
    #pragma unroll
    for (int d = 1; d < 64; d <<= 1) {
      int y = __shfl_up(inc, d, 64);
      if (lane >= d) inc += y;
    }
    off[lane] = inc - run;
  }
  __syncthreads();

  int* sp = sorted_pos + ((size_t)b * R_ + r) * L_;
  unsigned char* cp = cpack + (size_t)b * L_ * 4 + r;
  #pragma unroll
  for (int u = 0; u < 4; ++u) {
    int g = w * 4 + u;
    int bin = binv[u];
    int slot = off[bin] + hist[g * 65 + bin] + rank[u];
    sp[slot] = g * 64 + lane;
    cp[(size_t)(g * 64 + lane) * 4] = (unsigned char)(slot >> 6);
  }
}

// ---------------- Kernel 3: per-chunk attention (bf16 MFMA, R11 form) --------
__global__ __launch_bounds__(256) void attn_kernel(
    const unsigned short* __restrict__ Qn, const unsigned short* __restrict__ Vb,
    const float* __restrict__ qscale,
    const int* __restrict__ sorted_pos, const int* __restrict__ bucket,
    const int* __restrict__ cpack,
    unsigned short* __restrict__ att, float* __restrict__ lse_s) {
  int wg = (int)blockIdx.x;
  wg = (wg & 7) * (B_ * R_ * NB_ / 8) + (wg >> 3);   // XCD-contiguous swizzle
  int n = wg & 63;
  int r = (wg >> 6) & 3;
  int b = wg >> 8;
  int br = b * R_ + r;
  int nprev = (n + 63) & 63;

  __shared__ __align__(16) short bufK[128 * 64];   // K_norm bf16; reused as VT[64][128]
  __shared__ int skpos[128];
  __shared__ int skcode[128];                      // (bucket<<12) | pos
  __shared__ int sck[128];                         // packed chunk ids (4x8b)

  int t = threadIdx.x;
  if (t < 128) {
    int chunk = (t < 64) ? nprev : n;
    int pos = sorted_pos[(size_t)br * L_ + chunk * 64 + (t & 63)];
    skpos[t] = pos;
    skcode[t] = (bucket[((size_t)b * L_ + pos) * 4 + r] << 12) | pos;
    sck[t] = ((const int*)cpack)[(size_t)b * L_ + pos];
  }
  __syncthreads();

  int l = t & 63, w = t >> 6;
  int g = l >> 4, c = l & 15;
  int qi = w * 16 + c;

  // ---- K staging from Qn (bf16, swizzled LDS image) ----
  {
    int j = t >> 1, half = t & 1;
    const uint4* src = (const uint4*)(Qn + ((size_t)b * L_ + skpos[j]) * 64 + half * 32);
    short* krow = bufK + j * 64;
    int sz = swz(j);
    #pragma unroll
    for (int u = 0; u < 4; ++u)
      *(uint4*)(krow + (((half * 4 + u) ^ sz) << 3)) = src[u];
  }
  int qcode = skcode[64 + qi];
  int qpos = qcode & 4095;
  float csc = qscale[(size_t)b * L_ + qpos];   // issued early; used post-QK
  __syncthreads();

  // ---- QK^T via MFMA, SWAPPED: D = K_frag · Q_frag = S^T ----
  f32x4 acc[8];
  #pragma unroll
  for (int tt = 0; tt < 8; ++tt) acc[tt] = (f32x4){0.f, 0.f, 0.f, 0.f};
  {
    int qrow = 64 + qi;
    const short* qp_ = bufK + qrow * 64;
    bf16x8 q0 = *(const bf16x8*)(qp_ + (((g) ^ swz(qrow)) << 3));
    bf16x8 q1 = *(const bf16x8*)(qp_ + (((4 + g) ^ swz(qrow)) << 3));
    #pragma unroll
    for (int tt = 0; tt < 8; ++tt) {
      int krow = tt * 16 + c;
      const short* kp_ = bufK + krow * 64;
      bf16x8 k0 = *(const bf16x8*)(kp_ + (((g) ^ swz(krow)) << 3));
      bf16x8 k1 = *(const bf16x8*)(kp_ + (((4 + g) ^ swz(krow)) << 3));
      acc[tt] = __builtin_amdgcn_mfma_f32_16x16x32_bf16(k0, q0, acc[tt], 0, 0, 0);
      acc[tt] = __builtin_amdgcn_mfma_f32_16x16x32_bf16(k1, q1, acc[tt], 0, 0, 0);
    }
  }
  __syncthreads();   // all waves done reading bufK (VT will overwrite)

  // ---- issue V gathers early (bf16); consumed after softmax ----
  int pi = t >> 2, qd = t & 3;
  const uint4* vr0 = (const uint4*)(Vb + ((size_t)b * L_ + skpos[2 * pi]) * 64 + qd * 16);
  const uint4* vr1 = (const uint4*)(Vb + ((size_t)b * L_ + skpos[2 * pi + 1]) * 64 + qd * 16);
  uint4 A0 = vr0[0], A1 = vr0[1];
  uint4 B0 = vr1[0], B1 = vr1[1];

  // ---- masks + lane-local softmax (exp2 domain) ----
  unsigned aq = (unsigned)sck[64 + qi] | 0x40404040u;

  float m = -1e30f;
  #pragma unroll
  for (int tt = 0; tt < 8; ++tt) {
    int4 kc = *(const int4*)(skcode + tt * 16 + g * 4);
    #pragma unroll
    for (int j = 0; j < 4; ++j) {
      int kcode = (j == 0) ? kc.x : (j == 1) ? kc.y : (j == 2) ? kc.z : kc.w;
      float s = acc[tt][j] * csc;
      unsigned x = (unsigned)(qcode ^ kcode);
      s = ((qcode < kcode) || (x >= 4096u)) ? -1e9f : s;
      s = (x == 0u) ? -144269.5f : s;   // -1e5 * log2e
      acc[tt][j] = s;
      m = fmaxf(m, s);
    }
  }
  m = fmaxf(m, __shfl_xor(m, 16));
  m = fmaxf(m, __shfl_xor(m, 32));
  float sum = 0.f;
  #pragma unroll
  for (int tt = 0; tt < 8; ++tt) {
    #pragma unroll
    for (int j = 0; j < 4; ++j) {
      float e = exp2f(acc[tt][j] - m);
      acc[tt][j] = e;
      sum += e;
    }
  }
  sum += __shfl_xor(sum, 16);
  sum += __shfl_xor(sum, 32);
  float lse = 0.69314718f * (m + __log2f(sum));
  float isum = 1.0f / sum;
  if (l < 16) lse_s[(size_t)br * L_ + qpos] = lse;

  // ---- dup-count (SWAR) -> final P in registers ----
  #pragma unroll
  for (int tt = 0; tt < 8; ++tt) {
    int4 c4v = *(const int4*)(sck + tt * 16 + g * 4);
    #pragma unroll
    for (int j = 0; j < 4; ++j) {
      int ckv = (j == 0) ? c4v.x : (j == 1) ? c4v.y : (j == 2) ? c4v.z : c4v.w;
      unsigned e = (aq - (unsigned)ckv) & 0x3E3E3E3Eu;
      unsigned y = (e - 0x01010101u) & ~e & 0x80808080u;
      float cntf = (float)__popc(y);
      acc[tt][j] = acc[tt][j] * isum * __builtin_amdgcn_rcpf(cntf);
    }
  }

  // ---- P -> bf16 pairs in registers ----
  unsigned pk01[8], pk23[8];
  #pragma unroll
  for (int tt = 0; tt < 8; ++tt) {
    pk01[tt] = cvtpk(acc[tt][0], acc[tt][1]);
    pk23[tt] = cvtpk(acc[tt][2], acc[tt][3]);
  }

  // ---- VT staging into freed bufK (transpose from bf16 regs) ----
  short* VT = bufK;
  {
    unsigned Aw[8] = {A0.x, A0.y, A0.z, A0.w, A1.x, A1.y, A1.z, A1.w};
    unsigned Bw[8] = {B0.x, B0.y, B0.z, B0.w, B1.x, B1.y, B1.z, B1.w};
    int k0 = 2 * pi;
    #pragma unroll
    for (int i = 0; i < 8; ++i) {
      unsigned lo = (Aw[i] & 0xffffu) | (Bw[i] << 16);
      unsigned hi = (Aw[i] >> 16) | (Bw[i] & 0xffff0000u);
      int dl = qd * 16 + 2 * i, dh = dl + 1;
      *(unsigned*)(VT + dl * 128 + (((k0 >> 3) ^ swz(dl)) << 3) + (k0 & 7)) = lo;
      *(unsigned*)(VT + dh * 128 + (((k0 >> 3) ^ swz(dh)) << 3) + (k0 & 7)) = hi;
    }
  }
  __syncthreads();

  // ---- PV via MFMA: O^T[d][q] = sum_k VT[d][k] * P^T[k][q] ----
  f32x4 o[4];
  #pragma unroll
  for (int nt = 0; nt < 4; ++nt) o[nt] = (f32x4){0.f, 0.f, 0.f, 0.f};
  {
    int src  = (g & 1) * 32 + c;
    int srcB = src + 16;
    bool sel = (l >= 32);
    #pragma unroll
    for (int ks = 0; ks < 4; ++ks) {
      unsigned xA = __shfl(pk01[2 * ks], src),  yA = __shfl(pk01[2 * ks + 1], src);
      unsigned xB = __shfl(pk23[2 * ks], src),  yB = __shfl(pk23[2 * ks + 1], src);
      unsigned xC = __shfl(pk01[2 * ks], srcB), yC = __shfl(pk01[2 * ks + 1], srcB);
      unsigned xD = __shfl(pk23[2 * ks], srcB), yD = __shfl(pk23[2 * ks + 1], srcB);
      union { uint4 u; bf16x8 v; } bp;
      bp.u.x = sel ? yA : xA;
      bp.u.y = sel ? yB : xB;
      bp.u.z = sel ? yC : xC;
      bp.u.w = sel ? yD : xD;
      #pragma unroll
      for (int nt = 0; nt < 4; ++nt) {
        int vrow = nt * 16 + c;
        bf16x8 av = *(const bf16x8*)(VT + vrow * 128 + (((ks * 4 + g) ^ swz(vrow)) << 3));
        o[nt] = __builtin_amdgcn_mfma_f32_16x16x32_bf16(av, bp.v, o[nt], 0, 0, 0);
      }
    }
  }

  // ---- scatter att rows (bf16, 8B stores): lane owns one q-row ----
  {
    unsigned short* arow = att + ((size_t)br * L_ + qpos) * DK_;
    #pragma unroll
    for (int nt = 0; nt < 4; ++nt) {
      unsigned p0 = cvtpk(o[nt][0], o[nt][1]);
      unsigned p1 = cvtpk(o[nt][2], o[nt][3]);
      *(uint2*)(arow + nt * 16 + g * 4) = make_uint2(p0, p1);
    }
  }
}

// ---------------- Kernel 4: softmax reduction over L of lse ------------------
__global__ __launch_bounds__(256) void lsered_kernel(
    const float* __restrict__ lse_s, float* __restrict__ wred) {
  int br = blockIdx.x;
  const float* row = lse_s + (size_t)br * L_;
  __shared__ float red[4];
  int t = threadIdx.x;
  float m = -1e30f;
  for (int p = t; p < L_; p += 256) m = fmaxf(m, row[p]);
  #pragma unroll
  for (int mask = 1; mask < 64; mask <<= 1) m = fmaxf(m, __shfl_xor(m, mask, 64));
  if ((t & 63) == 0) red[t >> 6] = m;
  __syncthreads();
  m = fmaxf(fmaxf(red[0], red[1]), fmaxf(red[2], red[3]));
  __syncthreads();
  float sum = 0.f;
  for (int p = t; p < L_; p += 256) sum += __expf(row[p] - m);
  #pragma unroll
  for (int mask = 1; mask < 64; mask <<= 1) sum += __shfl_xor(sum, mask, 64);
  if ((t & 63) == 0) red[t >> 6] = sum;
  __syncthreads();
  if (t == 0) {
    wred[br * 2] = m;
    wred[br * 2 + 1] = red[0] + red[1] + red[2] + red[3];
  }
}

// ---------------- Kernel 5: weighted combine over rounds ---------------------
__global__ __launch_bounds__(256) void combine_kernel(
    const unsigned short* __restrict__ att, const float* __restrict__ lse_s,
    const float* __restrict__ wred, float* __restrict__ out) {
  int idx = blockIdx.x * 256 + threadIdx.x;
  int dq = idx & 3;
  int l = (idx >> 2) & (L_ - 1);
  int b = idx >> 14;
  float wv[4];
  #pragma unroll
  for (int r = 0; r < R_; ++r) {
    float m = wred[(b * R_ + r) * 2];
    float sinv = 1.0f / wred[(b * R_ + r) * 2 + 1];
    wv[r] = __expf(lse_s[((size_t)b * R_ + r) * L_ + l] - m) * sinv;
  }
  #pragma unroll
  for (int u = 0; u < 4; ++u) {
    int d4 = dq * 4 + u;
    float4 o = make_float4(0.f, 0.f, 0.f, 0.f);
    #pragma unroll
    for (int r = 0; r < R_; ++r) {
      ushort4 a = *(const ushort4*)(att + ((((size_t)b * R_ + r) * L_ + l) * 16 + d4) * 4);
      o.x += wv[r] * bf2f(a.x); o.y += wv[r] * bf2f(a.y);
      o.z += wv[r] * bf2f(a.z); o.w += wv[r] * bf2f(a.w);
    }
    ((float4*)out)[((size_t)b * L_ + l) * 16 + d4] = o;
  }
}

extern "C" void kernel_launch(void* const* d_in, const int* in_sizes, int n_in,
                              void* d_out, int out_size, void* d_ws, size_t ws_size,
                              hipStream_t stream) {
  const float* query = (const float*)d_in[0];
  const float* value = (const float*)d_in[1];
  const float* rm    = (const float*)d_in[2];
  (void)in_sizes; (void)n_in; (void)out_size; (void)ws_size;

  char* ws = (char*)d_ws;
  const size_t ATT_BYTES = (size_t)B_ * R_ * L_ * DK_ * 2;  // 32 MiB (bf16)
  const size_t MB = 1048576;
  unsigned short* att        = (unsigned short*)ws;
  int*            bucket     = (int*)(ws + ATT_BYTES);
  int*            sorted_pos = (int*)(ws + ATT_BYTES + 1 * MB);
  unsigned char*  cpack      = (unsigned char*)(ws + ATT_BYTES + 2 * MB);
  float*          lse_s      = (float*)(ws + ATT_BYTES + 3 * MB);
  float*          wred       = (float*)(ws + ATT_BYTES + 4 * MB);
  float*          qscale     = (float*)(ws + ATT_BYTES + 6 * MB);
  unsigned short* Qn         = (unsigned short*)(ws + ATT_BYTES + 8 * MB);
  unsigned short* Vb         = (unsigned short*)(ws + ATT_BYTES + 16 * MB);
  int*            cnt        = (int*)(ws + ATT_BYTES + 24 * MB);
  int*            flaglist   = (int*)(ws + ATT_BYTES + 25 * MB);
  float* out = (float*)d_out;

  zc_kernel<<<1, 1, 0, stream>>>(cnt);
  hash_kernel<<<B_ * 64, 256, 0, stream>>>(query, value, rm, bucket, Qn, qscale,
                                           Vb, cnt, flaglist);
  fixup_kernel<<<4096, 64, 0, stream>>>(query, rm, flaglist, cnt, bucket);
  sort_kernel<<<B_ * R_, 1024, 0, stream>>>(bucket, sorted_pos, cpack);
  attn_kernel<<<B_ * R_ * NB_, 256, 0, stream>>>(Qn, Vb, qscale, sorted_pos,
                                                 bucket, (const int*)cpack,
                                                 att, lse_s);
  lsered_kernel<<<B_ * R_, 256, 0, stream>>>(lse_s, wred);
  combine_kernel<<<(B_ * L_ * 4) / 256, 256, 0, stream>>>(att, lse_s, wred, out);
}

// Round 19
// 118.798 us; speedup vs baseline: 8.9571x; 1.0309x over previous
//
#include <hip/hip_runtime.h>

#define B_ 16
#define L_ 4096
#define DK_ 64
#define R_ 4
#define NB_ 64
#define BL_ 64
#define MAXFLAG 65536
#define THRESH 4e-3f

typedef __attribute__((ext_vector_type(8))) short bf16x8;
typedef __attribute__((ext_vector_type(4))) float f32x4;

__device__ __forceinline__ float bf2f(unsigned short u) {
  return __uint_as_float(((unsigned)u) << 16);
}
// HW packed f32->bf16 (RNE) — 1 inst per 2 values
__device__ __forceinline__ unsigned cvtpk(float lo, float hi) {
  unsigned r;
  asm("v_cvt_pk_bf16_f32 %0, %1, %2" : "=v"(r) : "v"(lo), "v"(hi));
  return r;
}
__device__ __forceinline__ int swz(int row) { return (row & 7) ^ ((row >> 3) & 7); }

// ---- Kernel 0: zero the flag counter ----------------------------------------
__global__ void zc_kernel(int* cnt) { *cnt = 0; }

// ---- Kernel 1: LSH hashing — fp32, unroll-2 acc loops (bounded ILP) ---------
// R18 was latency-bound at unroll 1 (VALUBusy 24%); R16/17 spilled at full
// unroll. unroll 2 + launch_bounds(256,4) bounds pressure at <=128 VGPR.
__global__ __launch_bounds__(256, 4) void hash_kernel(
    const float* __restrict__ query, const float* __restrict__ value,
    const float* __restrict__ rm, int* __restrict__ bucket,
    unsigned short* __restrict__ Qn, float* __restrict__ qscale,
    unsigned short* __restrict__ Vb,
    int* __restrict__ cnt, int* __restrict__ flaglist) {
  __shared__ float qs[64 * 68];      // q[tok][d], stride 68   (17408B)
  __shared__ float rs[32 * 160];     // rm half-d [32][cg*20]  (20480B)
  __shared__ float ssinf[128];       // (512B)
  __shared__ int sb[64 * 4];         // (1024B)

  int b = blockIdx.x >> 6;
  int tok0 = (blockIdx.x & 63) << 6;   // 64 tokens per block
  int t = threadIdx.x;

  {  // stage q: 64 tok x 16 float4
    const float4* qg = (const float4*)(query + ((size_t)b * L_ + tok0) * DK_);
    #pragma unroll
    for (int u = 0; u < 4; ++u) {
      int i = t + u * 256;
      int tokl = i >> 4, c4 = i & 15;
      *(float4*)(qs + tokl * 68 + c4 * 4) = qg[i];
    }
  }
  {  // stage rm rows d = 0..31 into padded-cg layout
    const float4* rg = (const float4*)(rm + (size_t)b * (DK_ * 128));
    #pragma unroll
    for (int u = 0; u < 4; ++u) {
      int i = t + u * 256;
      int d = i >> 5, c4 = i & 31;
      int cg2 = c4 >> 2, j4 = c4 & 3;
      *(float4*)(rs + d * 160 + cg2 * 20 + j4 * 4) = rg[i];
    }
  }
  __syncthreads();

  // ssin partial over d = 0..31 (fp32, rolled)
  float ssp = 0.f;
  if (t < 128) {
    const float* colp = rs + (t >> 4) * 20 + (t & 15);
    #pragma unroll 1
    for (int d = 0; d < 32; ++d) {
      float v = colp[d * 160];
      ssp += v * v;
    }
  }

  int cg = t & 7;
  int tg = t >> 3;
  float acc0[16], acc1[16];
  #pragma unroll
  for (int j = 0; j < 16; ++j) { acc0[j] = 0.f; acc1[j] = 0.f; }

  const float* q0 = qs + (tg * 2 + 0) * 68;
  const float* q1 = qs + (tg * 2 + 1) * 68;
  const float* rp = rs + cg * 20;

  // ---- acc part 1: d = 0..31 (unroll 2: two iterations in flight) ----
  #pragma unroll 2
  for (int d4 = 0; d4 < 8; ++d4) {
    float4 qa4 = *(const float4*)(q0 + d4 * 4);
    float4 qb4 = *(const float4*)(q1 + d4 * 4);
    #pragma unroll
    for (int sub = 0; sub < 4; ++sub) {
      float qa = (sub == 0) ? qa4.x : (sub == 1) ? qa4.y : (sub == 2) ? qa4.z : qa4.w;
      float qb = (sub == 0) ? qb4.x : (sub == 1) ? qb4.y : (sub == 2) ? qb4.z : qb4.w;
      const float* rr = rp + (d4 * 4 + sub) * 160;
      #pragma unroll
      for (int j4 = 0; j4 < 4; ++j4) {
        float4 rv = *(const float4*)(rr + j4 * 4);
        acc0[j4 * 4 + 0] += qa * rv.x; acc0[j4 * 4 + 1] += qa * rv.y;
        acc0[j4 * 4 + 2] += qa * rv.z; acc0[j4 * 4 + 3] += qa * rv.w;
        acc1[j4 * 4 + 0] += qb * rv.x; acc1[j4 * 4 + 1] += qb * rv.y;
        acc1[j4 * 4 + 2] += qb * rv.z; acc1[j4 * 4 + 3] += qb * rv.w;
      }
    }
  }
  __syncthreads();   // everyone done reading rs half 1

  {  // stage rm rows d = 32..63
    const float4* rg = (const float4*)(rm + (size_t)b * (DK_ * 128)) + 1024;
    #pragma unroll
    for (int u = 0; u < 4; ++u) {
      int i = t + u * 256;
      int d = i >> 5, c4 = i & 31;
      int cg2 = c4 >> 2, j4 = c4 & 3;
      *(float4*)(rs + d * 160 + cg2 * 20 + j4 * 4) = rg[i];
    }
  }
  __syncthreads();

  // ssin finish over d = 32..63 (rolled)
  if (t < 128) {
    const float* colp = rs + (t >> 4) * 20 + (t & 15);
    #pragma unroll 1
    for (int d = 0; d < 32; ++d) {
      float v = colp[d * 160];
      ssp += v * v;
    }
    ssinf[t] = 1.0f / sqrtf(ssp);
  }

  // ---- acc part 2: d = 32..63 (unroll 2) ----
  #pragma unroll 2
  for (int d4 = 8; d4 < 16; ++d4) {
    float4 qa4 = *(const float4*)(q0 + d4 * 4);
    float4 qb4 = *(const float4*)(q1 + d4 * 4);
    #pragma unroll
    for (int sub = 0; sub < 4; ++sub) {
      float qa = (sub == 0) ? qa4.x : (sub == 1) ? qa4.y : (sub == 2) ? qa4.z : qa4.w;
      float qb = (sub == 0) ? qb4.x : (sub == 1) ? qb4.y : (sub == 2) ? qb4.z : qb4.w;
      const float* rr = rp + ((d4 - 8) * 4 + sub) * 160;
      #pragma unroll
      for (int j4 = 0; j4 < 4; ++j4) {
        float4 rv = *(const float4*)(rr + j4 * 4);
        acc0[j4 * 4 + 0] += qa * rv.x; acc0[j4 * 4 + 1] += qa * rv.y;
        acc0[j4 * 4 + 2] += qa * rv.z; acc0[j4 * 4 + 3] += qa * rv.w;
        acc1[j4 * 4 + 0] += qb * rv.x; acc1[j4 * 4 + 1] += qb * rv.y;
        acc1[j4 * 4 + 2] += qb * rv.z; acc1[j4 * 4 + 3] += qb * rv.w;
      }
    }
  }
  __syncthreads();   // ssinf final visible to all

  // ---- branchless top-2 argmax (fp32) ----
  float bv0 = -1e30f, bs0 = -1e30f;
  float bv1 = -1e30f, bs1 = -1e30f;
  int bi0 = 0, bi1 = 0;
  int nbase = (cg & 1) * 16;
  #pragma unroll
  for (int j = 0; j < 16; ++j) {
    int col = cg * 16 + j;
    float sv = ssinf[col];
    int n = nbase + j;
    float v0 = acc0[j] * sv;
    float v1 = acc1[j] * sv;
    bs0 = fmaxf(bs0, fminf(bv0, v0));
    bi0 = (v0 > bv0) ? n : bi0;
    bv0 = fmaxf(bv0, v0);
    float w0 = -v0;
    bs0 = fmaxf(bs0, fminf(bv0, w0));
    bi0 = (w0 > bv0) ? (n + 32) : bi0;
    bv0 = fmaxf(bv0, w0);
    bs1 = fmaxf(bs1, fminf(bv1, v1));
    bi1 = (v1 > bv1) ? n : bi1;
    bv1 = fmaxf(bv1, v1);
    float w1 = -v1;
    bs1 = fmaxf(bs1, fminf(bv1, w1));
    bi1 = (w1 > bv1) ? (n + 32) : bi1;
    bv1 = fmaxf(bv1, w1);
  }
  {  // merge the two half-round threads (cg even/odd), branchless
    float ov, os; int oi;
    ov = __shfl_xor(bv0, 1); os = __shfl_xor(bs0, 1); oi = __shfl_xor(bi0, 1);
    bs0 = fmaxf(fmaxf(bs0, os), fminf(bv0, ov));
    bi0 = (ov > bv0) ? oi : bi0;
    bv0 = fmaxf(bv0, ov);
    ov = __shfl_xor(bv1, 1); os = __shfl_xor(bs1, 1); oi = __shfl_xor(bi1, 1);
    bs1 = fmaxf(fmaxf(bs1, os), fminf(bv1, ov));
    bi1 = (ov > bv1) ? oi : bi1;
    bv1 = fmaxf(bv1, ov);
  }
  if ((cg & 1) == 0) {
    int rr_ = cg >> 1;
    sb[(tg * 2 + 0) * 4 + rr_] = bi0;
    sb[(tg * 2 + 1) * 4 + rr_] = bi1;
    if (bv0 - bs0 < THRESH) {
      int ix = atomicAdd(cnt, 1);
      if (ix < MAXFLAG) flaglist[ix] = (b << 14) | ((tok0 + tg * 2 + 0) << 2) | rr_;
    }
    if (bv1 - bs1 < THRESH) {
      int ix = atomicAdd(cnt, 1);
      if (ix < MAXFLAG) flaglist[ix] = (b << 14) | ((tok0 + tg * 2 + 1) << 2) | rr_;
    }
  }
  __syncthreads();
  if (t < 64)
    ((int4*)bucket)[(size_t)b * L_ + tok0 + t] = ((int4*)sb)[t];

  // ---- emit normalized bf16 Q rows + scale (exact same reduction order) ----
  if (t < 128) {
    int row = t >> 1, half = t & 1;
    const float* qp = qs + row * 68 + half * 32;
    float v[32];
    float ss = 0.f;
    #pragma unroll
    for (int u = 0; u < 8; ++u) {
      float4 x = *(const float4*)(qp + u * 4);
      v[u*4+0] = x.x; v[u*4+1] = x.y; v[u*4+2] = x.z; v[u*4+3] = x.w;
      ss += x.x*x.x + x.y*x.y + x.z*x.z + x.w*x.w;
    }
    ss += __shfl_xor(ss, 1);
    float inv = 1.0f / fmaxf(sqrtf(ss), 1e-12f);
    unsigned short* qn = Qn + ((size_t)b * L_ + tok0 + row) * 64 + half * 32;
    #pragma unroll
    for (int u = 0; u < 4; ++u) {
      uint4 pk;
      pk.x = cvtpk(v[u*8+0] * inv, v[u*8+1] * inv);
      pk.y = cvtpk(v[u*8+2] * inv, v[u*8+3] * inv);
      pk.z = cvtpk(v[u*8+4] * inv, v[u*8+5] * inv);
      pk.w = cvtpk(v[u*8+6] * inv, v[u*8+7] * inv);
      ((uint4*)qn)[u] = pk;
    }
    if (half == 0)
      qscale[(size_t)b * L_ + tok0 + row] = 0.18033688f / inv;  // 0.125*log2e*|q|
  }

  // ---- convert this block's V rows to bf16 (adjacent-pair cvtpk) ----
  {
    int row = t >> 2, qd = t & 3;
    const float* vr = value + ((size_t)b * L_ + tok0 + row) * DK_ + qd * 16;
    float4 x0 = ((const float4*)vr)[0], x1 = ((const float4*)vr)[1],
           x2 = ((const float4*)vr)[2], x3 = ((const float4*)vr)[3];
    uint4 p0, p1;
    p0.x = cvtpk(x0.x, x0.y); p0.y = cvtpk(x0.z, x0.w);
    p0.z = cvtpk(x1.x, x1.y); p0.w = cvtpk(x1.z, x1.w);
    p1.x = cvtpk(x2.x, x2.y); p1.y = cvtpk(x2.z, x2.w);
    p1.z = cvtpk(x3.x, x3.y); p1.w = cvtpk(x3.z, x3.w);
    unsigned short* out = Vb + ((size_t)b * L_ + tok0 + row) * 64 + qd * 16;
    ((uint4*)out)[0] = p0;
    ((uint4*)out)[1] = p1;
  }
}

// ---- Kernel 1.5: exact fp64 fixup for margin-flagged decisions --------------
__global__ __launch_bounds__(64) void fixup_kernel(
    const float* __restrict__ query, const float* __restrict__ rm,
    const int* __restrict__ flaglist, const int* __restrict__ cnt,
    int* __restrict__ bucket) {
  int nfl = *cnt;
  if (nfl > MAXFLAG) nfl = MAXFLAG;
  int lane = threadIdx.x;
  for (int i = blockIdx.x; i < nfl; i += gridDim.x) {
    int code = flaglist[i];
    int r = code & 3, l = (code >> 2) & 4095, b = code >> 14;
    int col = r * 32 + (lane & 31);
    const float* qrow = query + ((size_t)b * L_ + l) * DK_;
    const float* rmc = rm + (size_t)b * (DK_ * 128) + col;
    double acc = 0.0, ss = 0.0;
    for (int d = 0; d < DK_; ++d) {
      double qv = (double)qrow[d];
      double rv = (double)rmc[d * 128];
      acc += qv * rv;
      ss += rv * rv;
    }
    double sinv = 1.0 / sqrt(ss);
    double v = acc * sinv;
    double bv = (lane < 32) ? v : -v;
    int bi = lane;
    #pragma unroll
    for (int msk = 1; msk < 64; msk <<= 1) {
      double ov = __shfl_xor(bv, msk);
      int oi = __shfl_xor(bi, msk);
      if (ov > bv || (ov == bv && oi < bi)) { bv = ov; bi = oi; }
    }
    if (lane == 0) bucket[((size_t)b * L_ + l) * 4 + r] = bi;
  }
}

// ------- Kernel 2: 16-wave two-level stable counting sort per (b, r) --------
__global__ __launch_bounds__(1024) void sort_kernel(
    const int* __restrict__ bucket, int* __restrict__ sorted_pos,
    unsigned char* __restrict__ cpack) {
  int b = blockIdx.x >> 2;
  int r = blockIdx.x & 3;
  __shared__ int hist[64 * 65];   // [chunk][bin], stride 65
  __shared__ int off[64];
  int t = threadIdx.x, lane = t & 63, w = t >> 6;
  unsigned long long ltmask = (1ull << lane) - 1ull;
  const int* bb = bucket + (size_t)b * L_ * 4 + r;

  int binv[4], rank[4];
  #pragma unroll
  for (int u = 0; u < 4; ++u)
    binv[u] = bb[(size_t)((w * 4 + u) * 64 + lane) * 4];

  for (int idx = t; idx < 64 * 65; idx += 1024) hist[idx] = 0;
  __syncthreads();

  #pragma unroll
  for (int u = 0; u < 4; ++u) {
    int bin = binv[u];
    unsigned long long m = ~0ull;
    #pragma unroll
    for (int k = 0; k < 6; ++k) {
      unsigned long long bal = __ballot((bin >> k) & 1);
      m &= ((bin >> k) & 1) ? bal : ~bal;
    }
    rank[u] = (int)__popcll(m & ltmask);
    if (rank[u] == 0) hist[(w * 4 + u) * 65 + bin] = (int)__popcll(m);
  }
  __syncthreads();

  if (w == 0) {
    int run = 0;
    for (int g = 0; g < 64; ++g) {
      int v = hist[g * 65 + lane];
      hist[g * 65 + lane] = run;
      run += v;
    }
    int inc = run;
    #pragma unroll
    for (int d = 1; d < 64; d <<= 1) {
      int y = __shfl_up(inc, d, 64);
      if (lane >= d) inc += y;
    }
    off[lane] = inc - run;
  }
  __syncthreads();

  int* sp = sorted_pos + ((size_t)b * R_ + r) * L_;
  unsigned char* cp = cpack + (size_t)b * L_ * 4 + r;
  #pragma unroll
  for (int u = 0; u < 4; ++u) {
    int g = w * 4 + u;
    int bin = binv[u];
    int slot = off[bin] + hist[g * 65 + bin] + rank[u];
    sp[slot] = g * 64 + lane;
    cp[(size_t)(g * 64 + lane) * 4] = (unsigned char)(slot >> 6);
  }
}

// ---------------- Kernel 3: per-chunk attention (bf16 MFMA, R11 form) --------
__global__ __launch_bounds__(256) void attn_kernel(
    const unsigned short* __restrict__ Qn, const unsigned short* __restrict__ Vb,
    const float* __restrict__ qscale,
    const int* __restrict__ sorted_pos, const int* __restrict__ bucket,
    const int* __restrict__ cpack,
    unsigned short* __restrict__ att, float* __restrict__ lse_s) {
  int wg = (int)blockIdx.x;
  wg = (wg & 7) * (B_ * R_ * NB_ / 8) + (wg >> 3);   // XCD-contiguous swizzle
  int n = wg & 63;
  int r = (wg >> 6) & 3;
  int b = wg >> 8;
  int br = b * R_ + r;
  int nprev = (n + 63) & 63;

  __shared__ __align__(16) short bufK[128 * 64];   // K_norm bf16; reused as VT[64][128]
  __shared__ int skpos[128];
  __shared__ int skcode[128];                      // (bucket<<12) | pos
  __shared__ int sck[128];                         // packed chunk ids (4x8b)

  int t = threadIdx.x;
  if (t < 128) {
    int chunk = (t < 64) ? nprev : n;
    int pos = sorted_pos[(size_t)br * L_ + chunk * 64 + (t & 63)];
    skpos[t] = pos;
    skcode[t] = (bucket[((size_t)b * L_ + pos) * 4 + r] << 12) | pos;
    sck[t] = ((const int*)cpack)[(size_t)b * L_ + pos];
  }
  __syncthreads();

  int l = t & 63, w = t >> 6;
  int g = l >> 4, c = l & 15;
  int qi = w * 16 + c;

  // ---- K staging from Qn (bf16, swizzled LDS image) ----
  {
    int j = t >> 1, half = t & 1;
    const uint4* src = (const uint4*)(Qn + ((size_t)b * L_ + skpos[j]) * 64 + half * 32);
    short* krow = bufK + j * 64;
    int sz = swz(j);
    #pragma unroll
    for (int u = 0; u < 4; ++u)
      *(uint4*)(krow + (((half * 4 + u) ^ sz) << 3)) = src[u];
  }
  int qcode = skcode[64 + qi];
  int qpos = qcode & 4095;
  float csc = qscale[(size_t)b * L_ + qpos];   // issued early; used post-QK
  __syncthreads();

  // ---- QK^T via MFMA, SWAPPED: D = K_frag · Q_frag = S^T ----
  f32x4 acc[8];
  #pragma unroll
  for (int tt = 0; tt < 8; ++tt) acc[tt] = (f32x4){0.f, 0.f, 0.f, 0.f};
  {
    int qrow = 64 + qi;
    const short* qp_ = bufK + qrow * 64;
    bf16x8 q0 = *(const bf16x8*)(qp_ + (((g) ^ swz(qrow)) << 3));
    bf16x8 q1 = *(const bf16x8*)(qp_ + (((4 + g) ^ swz(qrow)) << 3));
    #pragma unroll
    for (int tt = 0; tt < 8; ++tt) {
      int krow = tt * 16 + c;
      const short* kp_ = bufK + krow * 64;
      bf16x8 k0 = *(const bf16x8*)(kp_ + (((g) ^ swz(krow)) << 3));
      bf16x8 k1 = *(const bf16x8*)(kp_ + (((4 + g) ^ swz(krow)) << 3));
      acc[tt] = __builtin_amdgcn_mfma_f32_16x16x32_bf16(k0, q0, acc[tt], 0, 0, 0);
      acc[tt] = __builtin_amdgcn_mfma_f32_16x16x32_bf16(k1, q1, acc[tt], 0, 0, 0);
    }
  }
  __syncthreads();   // all waves done reading bufK (VT will overwrite)

  // ---- issue V gathers early (bf16); consumed after softmax ----
  int pi = t >> 2, qd = t & 3;
  const uint4* vr0 = (const uint4*)(Vb + ((size_t)b * L_ + skpos[2 * pi]) * 64 + qd * 16);
  const uint4* vr1 = (const uint4*)(Vb + ((size_t)b * L_ + skpos[2 * pi + 1]) * 64 + qd * 16);
  uint4 A0 = vr0[0], A1 = vr0[1];
  uint4 B0 = vr1[0], B1 = vr1[1];

  // ---- masks + lane-local softmax (exp2 domain) ----
  unsigned aq = (unsigned)sck[64 + qi] | 0x40404040u;

  float m = -1e30f;
  #pragma unroll
  for (int tt = 0; tt < 8; ++tt) {
    int4 kc = *(const int4*)(skcode + tt * 16 + g * 4);
    #pragma unroll
    for (int j = 0; j < 4; ++j) {
      int kcode = (j == 0) ? kc.x : (j == 1) ? kc.y : (j == 2) ? kc.z : kc.w;
      float s = acc[tt][j] * csc;
      unsigned x = (unsigned)(qcode ^ kcode);
      s = ((qcode < kcode) || (x >= 4096u)) ? -1e9f : s;
      s = (x == 0u) ? -144269.5f : s;   // -1e5 * log2e
      acc[tt][j] = s;
      m = fmaxf(m, s);
    }
  }
  m = fmaxf(m, __shfl_xor(m, 16));
  m = fmaxf(m, __shfl_xor(m, 32));
  float sum = 0.f;
  #pragma unroll
  for (int tt = 0; tt < 8; ++tt) {
    #pragma unroll
    for (int j = 0; j < 4; ++j) {
      float e = exp2f(acc[tt][j] - m);
      acc[tt][j] = e;
      sum += e;
    }
  }
  sum += __shfl_xor(sum, 16);
  sum += __shfl_xor(sum, 32);
  float lse = 0.69314718f * (m + __log2f(sum));
  float isum = 1.0f / sum;
  if (l < 16) lse_s[(size_t)br * L_ + qpos] = lse;

  // ---- dup-count (SWAR) -> final P in registers ----
  #pragma unroll
  for (int tt = 0; tt < 8; ++tt) {
    int4 c4v = *(const int4*)(sck + tt * 16 + g * 4);
    #pragma unroll
    for (int j = 0; j < 4; ++j) {
      int ckv = (j == 0) ? c4v.x : (j == 1) ? c4v.y : (j == 2) ? c4v.z : c4v.w;
      unsigned e = (aq - (unsigned)ckv) & 0x3E3E3E3Eu;
      unsigned y = (e - 0x01010101u) & ~e & 0x80808080u;
      float cntf = (float)__popc(y);
      acc[tt][j] = acc[tt][j] * isum * __builtin_amdgcn_rcpf(cntf);
    }
  }

  // ---- P -> bf16 pairs in registers ----
  unsigned pk01[8], pk23[8];
  #pragma unroll
  for (int tt = 0; tt < 8; ++tt) {
    pk01[tt] = cvtpk(acc[tt][0], acc[tt][1]);
    pk23[tt] = cvtpk(acc[tt][2], acc[tt][3]);
  }

  // ---- VT staging into freed bufK (transpose from bf16 regs) ----
  short* VT = bufK;
  {
    unsigned Aw[8] = {A0.x, A0.y, A0.z, A0.w, A1.x, A1.y, A1.z, A1.w};
    unsigned Bw[8] = {B0.x, B0.y, B0.z, B0.w, B1.x, B1.y, B1.z, B1.w};
    int k0 = 2 * pi;
    #pragma unroll
    for (int i = 0; i < 8; ++i) {
      unsigned lo = (Aw[i] & 0xffffu) | (Bw[i] << 16);
      unsigned hi = (Aw[i] >> 16) | (Bw[i] & 0xffff0000u);
      int dl = qd * 16 + 2 * i, dh = dl + 1;
      *(unsigned*)(VT + dl * 128 + (((k0 >> 3) ^ swz(dl)) << 3) + (k0 & 7)) = lo;
      *(unsigned*)(VT + dh * 128 + (((k0 >> 3) ^ swz(dh)) << 3) + (k0 & 7)) = hi;
    }
  }
  __syncthreads();

  // ---- PV via MFMA: O^T[d][q] = sum_k VT[d][k] * P^T[k][q] ----
  f32x4 o[4];
  #pragma unroll
  for (int nt = 0; nt < 4; ++nt) o[nt] = (f32x4){0.f, 0.f, 0.f, 0.f};
  {
    int src  = (g & 1) * 32 + c;
    int srcB = src + 16;
    bool sel = (l >= 32);
    #pragma unroll
    for (int ks = 0; ks < 4; ++ks) {
      unsigned xA = __shfl(pk01[2 * ks], src),  yA = __shfl(pk01[2 * ks + 1], src);
      unsigned xB = __shfl(pk23[2 * ks], src),  yB = __shfl(pk23[2 * ks + 1], src);
      unsigned xC = __shfl(pk01[2 * ks], srcB), yC = __shfl(pk01[2 * ks + 1], srcB);
      unsigned xD = __shfl(pk23[2 * ks], srcB), yD = __shfl(pk23[2 * ks + 1], srcB);
      union { uint4 u; bf16x8 v; } bp;
      bp.u.x = sel ? yA : xA;
      bp.u.y = sel ? yB : xB;
      bp.u.z = sel ? yC : xC;
      bp.u.w = sel ? yD : xD;
      #pragma unroll
      for (int nt = 0; nt < 4; ++nt) {
        int vrow = nt * 16 + c;
        bf16x8 av = *(const bf16x8*)(VT + vrow * 128 + (((ks * 4 + g) ^ swz(vrow)) << 3));
        o[nt] = __builtin_amdgcn_mfma_f32_16x16x32_bf16(av, bp.v, o[nt], 0, 0, 0);
      }
    }
  }

  // ---- scatter att rows (bf16, 8B stores): lane owns one q-row ----
  {
    unsigned short* arow = att + ((size_t)br * L_ + qpos) * DK_;
    #pragma unroll
    for (int nt = 0; nt < 4; ++nt) {
      unsigned p0 = cvtpk(o[nt][0], o[nt][1]);
      unsigned p1 = cvtpk(o[nt][2], o[nt][3]);
      *(uint2*)(arow + nt * 16 + g * 4) = make_uint2(p0, p1);
    }
  }
}

// ---------------- Kernel 4: softmax reduction over L of lse ------------------
__global__ __launch_bounds__(256) void lsered_kernel(
    const float* __restrict__ lse_s, float* __restrict__ wred) {
  int br = blockIdx.x;
  const float* row = lse_s + (size_t)br * L_;
  __shared__ float red[4];
  int t = threadIdx.x;
  float m = -1e30f;
  for (int p = t; p < L_; p += 256) m = fmaxf(m, row[p]);
  #pragma unroll
  for (int mask = 1; mask < 64; mask <<= 1) m = fmaxf(m, __shfl_xor(m, mask, 64));
  if ((t & 63) == 0) red[t >> 6] = m;
  __syncthreads();
  m = fmaxf(fmaxf(red[0], red[1]), fmaxf(red[2], red[3]));
  __syncthreads();
  float sum = 0.f;
  for (int p = t; p < L_; p += 256) sum += __expf(row[p] - m);
  #pragma unroll
  for (int mask = 1; mask < 64; mask <<= 1) sum += __shfl_xor(sum, mask, 64);
  if ((t & 63) == 0) red[t >> 6] = sum;
  __syncthreads();
  if (t == 0) {
    wred[br * 2] = m;
    wred[br * 2 + 1] = red[0] + red[1] + red[2] + red[3];
  }
}

// ---------------- Kernel 5: weighted combine over rounds ---------------------
__global__ __launch_bounds__(256) void combine_kernel(
    const unsigned short* __restrict__ att, const float* __restrict__ lse_s,
    const float* __restrict__ wred, float* __restrict__ out) {
  int idx = blockIdx.x * 256 + threadIdx.x;
  int dq = idx & 3;
  int l = (idx >> 2) & (L_ - 1);
  int b = idx >> 14;
  float wv[4];
  #pragma unroll
  for (int r = 0; r < R_; ++r) {
    float m = wred[(b * R_ + r) * 2];
    float sinv = 1.0f / wred[(b * R_ + r) * 2 + 1];
    wv[r] = __expf(lse_s[((size_t)b * R_ + r) * L_ + l] - m) * sinv;
  }
  #pragma unroll
  for (int u = 0; u < 4; ++u) {
    int d4 = dq * 4 + u;
    float4 o = make_float4(0.f, 0.f, 0.f, 0.f);
    #pragma unroll
    for (int r = 0; r < R_; ++r) {
      ushort4 a = *(const ushort4*)(att + ((((size_t)b * R_ + r) * L_ + l) * 16 + d4) * 4);
      o.x += wv[r] * bf2f(a.x); o.y += wv[r] * bf2f(a.y);
      o.z += wv[r] * bf2f(a.z); o.w += wv[r] * bf2f(a.w);
    }
    ((float4*)out)[((size_t)b * L_ + l) * 16 + d4] = o;
  }
}

extern "C" void kernel_launch(void* const* d_in, const int* in_sizes, int n_in,
                              void* d_out, int out_size, void* d_ws, size_t ws_size,
                              hipStream_t stream) {
  const float* query = (const float*)d_in[0];
  const float* value = (const float*)d_in[1];
  const float* rm    = (const float*)d_in[2];
  (void)in_sizes; (void)n_in; (void)out_size; (void)ws_size;

  char* ws = (char*)d_ws;
  const size_t ATT_BYTES = (size_t)B_ * R_ * L_ * DK_ * 2;  // 32 MiB (bf16)
  const size_t MB = 1048576;
  unsigned short* att        = (unsigned short*)ws;
  int*            bucket     = (int*)(ws + ATT_BYTES);
  int*            sorted_pos = (int*)(ws + ATT_BYTES + 1 * MB);
  unsigned char*  cpack      = (unsigned char*)(ws + ATT_BYTES + 2 * MB);
  float*          lse_s      = (float*)(ws + ATT_BYTES + 3 * MB);
  float*          wred       = (float*)(ws + ATT_BYTES + 4 * MB);
  float*          qscale     = (float*)(ws + ATT_BYTES + 6 * MB);
  unsigned short* Qn         = (unsigned short*)(ws + ATT_BYTES + 8 * MB);
  unsigned short* Vb         = (unsigned short*)(ws + ATT_BYTES + 16 * MB);
  int*            cnt        = (int*)(ws + ATT_BYTES + 24 * MB);
  int*            flaglist   = (int*)(ws + ATT_BYTES + 25 * MB);
  float* out = (float*)d_out;

  zc_kernel<<<1, 1, 0, stream>>>(cnt);
  hash_kernel<<<B_ * 64, 256, 0, stream>>>(query, value, rm, bucket, Qn, qscale,
                                           Vb, cnt, flaglist);
  fixup_kernel<<<4096, 64, 0, stream>>>(query, rm, flaglist, cnt, bucket);
  sort_kernel<<<B_ * R_, 1024, 0, stream>>>(bucket, sorted_pos, cpack);
  attn_kernel<<<B_ * R_ * NB_, 256, 0, stream>>>(Qn, Vb, qscale, sorted_pos,
                                                 bucket, (const int*)cpack,
                                                 att, lse_s);
  lsered_kernel<<<B_ * R_, 256, 0, stream>>>(lse_s, wred);
  combine_kernel<<<(B_ * L_ * 4) / 256, 256, 0, stream>>>(att, lse_s, wred, out);
}

// Round 20
// 116.527 us; speedup vs baseline: 9.1317x; 1.0195x over previous
//
#include <hip/hip_runtime.h>

#define B_ 16
#define L_ 4096
#define DK_ 64
#define R_ 4
#define NB_ 64
#define BL_ 64
#define MAXFLAG 65536
#define THRESH 4e-3f

typedef __attribute__((ext_vector_type(8))) short bf16x8;
typedef __attribute__((ext_vector_type(4))) float f32x4;

__device__ __forceinline__ float bf2f(unsigned short u) {
  return __uint_as_float(((unsigned)u) << 16);
}
// HW packed f32->bf16 (RNE) — 1 inst per 2 values
__device__ __forceinline__ unsigned cvtpk(float lo, float hi) {
  unsigned r;
  asm("v_cvt_pk_bf16_f32 %0, %1, %2" : "=v"(r) : "v"(lo), "v"(hi));
  return r;
}
__device__ __forceinline__ int swz(int row) { return (row & 7) ^ ((row >> 3) & 7); }

// ---- Kernel 0: zero the flag counter ----------------------------------------
__global__ void zc_kernel(int* cnt) { *cnt = 0; }

// ---- Kernel 1: LSH hashing — fp32, 4-token x 16-col tile --------------------
// LDS-read-throughput was the ~47us floor (288 b128/thread for 2 tokens).
// 4 tokens/thread halves LDS insts per FMA. 128 tok/block, full rs staged
// once (78.3KB LDS, 2 blocks/CU — R14-proven size). Margin flags -> fp64 fixup.
__global__ __launch_bounds__(256, 3) void hash_kernel(
    const float* __restrict__ query, const float* __restrict__ value,
    const float* __restrict__ rm, int* __restrict__ bucket,
    unsigned short* __restrict__ Qn, float* __restrict__ qscale,
    unsigned short* __restrict__ Vb,
    int* __restrict__ cnt, int* __restrict__ flaglist) {
  __shared__ float qs[128 * 68];     // q[tok][d], stride 68   (34816B)
  __shared__ float rs[64 * 160];     // rm[d][cg*20]           (40960B)
  __shared__ float ssinf[128];       // (512B)
  __shared__ int sb[128 * 4];        // (2048B)

  int b = blockIdx.x >> 5;
  int tok0 = (blockIdx.x & 31) << 7;   // 128 tokens per block
  int t = threadIdx.x;

  {  // stage q: 128 tok x 16 float4
    const float4* qg = (const float4*)(query + ((size_t)b * L_ + tok0) * DK_);
    #pragma unroll
    for (int u = 0; u < 8; ++u) {
      int i = t + u * 256;
      int tokl = i >> 4, c4 = i & 15;
      *(float4*)(qs + tokl * 68 + c4 * 4) = qg[i];
    }
  }
  {  // stage rm: 64 d x 32 float4 into padded-cg layout
    const float4* rg = (const float4*)(rm + (size_t)b * (DK_ * 128));
    #pragma unroll
    for (int u = 0; u < 8; ++u) {
      int i = t + u * 256;
      int d = i >> 5, c4 = i & 31;
      int cg2 = c4 >> 2, j4 = c4 & 3;
      *(float4*)(rs + d * 160 + cg2 * 20 + j4 * 4) = rg[i];
    }
  }
  __syncthreads();

  // column inverse norms (fp32, 4 independent partials -> short dep chains)
  if (t < 128) {
    const float* colp = rs + (t >> 4) * 20 + (t & 15);
    float s0 = 0.f, s1 = 0.f, s2 = 0.f, s3 = 0.f;
    #pragma unroll 4
    for (int d = 0; d < 64; d += 4) {
      float v0 = colp[(d + 0) * 160];
      float v1 = colp[(d + 1) * 160];
      float v2 = colp[(d + 2) * 160];
      float v3 = colp[(d + 3) * 160];
      s0 += v0 * v0; s1 += v1 * v1; s2 += v2 * v2; s3 += v3 * v3;
    }
    ssinf[t] = 1.0f / sqrtf((s0 + s1) + (s2 + s3));
  }

  int cg = t & 7;
  int tg = t >> 3;                     // 32 token groups of 4
  float acc0[16], acc1[16], acc2[16], acc3[16];
  #pragma unroll
  for (int j = 0; j < 16; ++j) { acc0[j] = 0.f; acc1[j] = 0.f; acc2[j] = 0.f; acc3[j] = 0.f; }

  const float* q0 = qs + (tg * 4 + 0) * 68;
  const float* q1 = qs + (tg * 4 + 1) * 68;
  const float* q2 = qs + (tg * 4 + 2) * 68;
  const float* q3 = qs + (tg * 4 + 3) * 68;
  const float* rp = rs + cg * 20;

  #pragma unroll 1
  for (int d4 = 0; d4 < 16; ++d4) {
    float4 qa4 = *(const float4*)(q0 + d4 * 4);
    float4 qb4 = *(const float4*)(q1 + d4 * 4);
    float4 qc4 = *(const float4*)(q2 + d4 * 4);
    float4 qd4 = *(const float4*)(q3 + d4 * 4);
    #pragma unroll
    for (int sub = 0; sub < 4; ++sub) {
      float qa = (sub == 0) ? qa4.x : (sub == 1) ? qa4.y : (sub == 2) ? qa4.z : qa4.w;
      float qb = (sub == 0) ? qb4.x : (sub == 1) ? qb4.y : (sub == 2) ? qb4.z : qb4.w;
      float qc = (sub == 0) ? qc4.x : (sub == 1) ? qc4.y : (sub == 2) ? qc4.z : qc4.w;
      float qd = (sub == 0) ? qd4.x : (sub == 1) ? qd4.y : (sub == 2) ? qd4.z : qd4.w;
      const float* rr = rp + (d4 * 4 + sub) * 160;
      #pragma unroll
      for (int j4 = 0; j4 < 4; ++j4) {
        float4 rv = *(const float4*)(rr + j4 * 4);
        acc0[j4 * 4 + 0] += qa * rv.x; acc0[j4 * 4 + 1] += qa * rv.y;
        acc0[j4 * 4 + 2] += qa * rv.z; acc0[j4 * 4 + 3] += qa * rv.w;
        acc1[j4 * 4 + 0] += qb * rv.x; acc1[j4 * 4 + 1] += qb * rv.y;
        acc1[j4 * 4 + 2] += qb * rv.z; acc1[j4 * 4 + 3] += qb * rv.w;
        acc2[j4 * 4 + 0] += qc * rv.x; acc2[j4 * 4 + 1] += qc * rv.y;
        acc2[j4 * 4 + 2] += qc * rv.z; acc2[j4 * 4 + 3] += qc * rv.w;
        acc3[j4 * 4 + 0] += qd * rv.x; acc3[j4 * 4 + 1] += qd * rv.y;
        acc3[j4 * 4 + 2] += qd * rv.z; acc3[j4 * 4 + 3] += qd * rv.w;
      }
    }
  }
  __syncthreads();   // ssinf visible

  // ---- branchless top-2 argmax (fp32), 4 tokens ----
  float bv0 = -1e30f, bs0 = -1e30f, bv1 = -1e30f, bs1 = -1e30f;
  float bv2 = -1e30f, bs2 = -1e30f, bv3 = -1e30f, bs3 = -1e30f;
  int bi0 = 0, bi1 = 0, bi2 = 0, bi3 = 0;
  int nbase = (cg & 1) * 16;
  #pragma unroll
  for (int j = 0; j < 16; ++j) {
    float sv = ssinf[cg * 16 + j];
    int n = nbase + j;
    float v, w;
    v = acc0[j] * sv; w = -v;
    bs0 = fmaxf(bs0, fminf(bv0, v)); bi0 = (v > bv0) ? n : bi0; bv0 = fmaxf(bv0, v);
    bs0 = fmaxf(bs0, fminf(bv0, w)); bi0 = (w > bv0) ? (n + 32) : bi0; bv0 = fmaxf(bv0, w);
    v = acc1[j] * sv; w = -v;
    bs1 = fmaxf(bs1, fminf(bv1, v)); bi1 = (v > bv1) ? n : bi1; bv1 = fmaxf(bv1, v);
    bs1 = fmaxf(bs1, fminf(bv1, w)); bi1 = (w > bv1) ? (n + 32) : bi1; bv1 = fmaxf(bv1, w);
    v = acc2[j] * sv; w = -v;
    bs2 = fmaxf(bs2, fminf(bv2, v)); bi2 = (v > bv2) ? n : bi2; bv2 = fmaxf(bv2, v);
    bs2 = fmaxf(bs2, fminf(bv2, w)); bi2 = (w > bv2) ? (n + 32) : bi2; bv2 = fmaxf(bv2, w);
    v = acc3[j] * sv; w = -v;
    bs3 = fmaxf(bs3, fminf(bv3, v)); bi3 = (v > bv3) ? n : bi3; bv3 = fmaxf(bv3, v);
    bs3 = fmaxf(bs3, fminf(bv3, w)); bi3 = (w > bv3) ? (n + 32) : bi3; bv3 = fmaxf(bv3, w);
  }
  {  // merge the two half-round threads (cg even/odd), branchless
    float ov, os; int oi;
    ov = __shfl_xor(bv0, 1); os = __shfl_xor(bs0, 1); oi = __shfl_xor(bi0, 1);
    bs0 = fmaxf(fmaxf(bs0, os), fminf(bv0, ov)); bi0 = (ov > bv0) ? oi : bi0; bv0 = fmaxf(bv0, ov);
    ov = __shfl_xor(bv1, 1); os = __shfl_xor(bs1, 1); oi = __shfl_xor(bi1, 1);
    bs1 = fmaxf(fmaxf(bs1, os), fminf(bv1, ov)); bi1 = (ov > bv1) ? oi : bi1; bv1 = fmaxf(bv1, ov);
    ov = __shfl_xor(bv2, 1); os = __shfl_xor(bs2, 1); oi = __shfl_xor(bi2, 1);
    bs2 = fmaxf(fmaxf(bs2, os), fminf(bv2, ov)); bi2 = (ov > bv2) ? oi : bi2; bv2 = fmaxf(bv2, ov);
    ov = __shfl_xor(bv3, 1); os = __shfl_xor(bs3, 1); oi = __shfl_xor(bi3, 1);
    bs3 = fmaxf(fmaxf(bs3, os), fminf(bv3, ov)); bi3 = (ov > bv3) ? oi : bi3; bv3 = fmaxf(bv3, ov);
  }
  if ((cg & 1) == 0) {
    int rr_ = cg >> 1;
    sb[(tg * 4 + 0) * 4 + rr_] = bi0;
    sb[(tg * 4 + 1) * 4 + rr_] = bi1;
    sb[(tg * 4 + 2) * 4 + rr_] = bi2;
    sb[(tg * 4 + 3) * 4 + rr_] = bi3;
    if (bv0 - bs0 < THRESH) {
      int ix = atomicAdd(cnt, 1);
      if (ix < MAXFLAG) flaglist[ix] = (b << 14) | ((tok0 + tg * 4 + 0) << 2) | rr_;
    }
    if (bv1 - bs1 < THRESH) {
      int ix = atomicAdd(cnt, 1);
      if (ix < MAXFLAG) flaglist[ix] = (b << 14) | ((tok0 + tg * 4 + 1) << 2) | rr_;
    }
    if (bv2 - bs2 < THRESH) {
      int ix = atomicAdd(cnt, 1);
      if (ix < MAXFLAG) flaglist[ix] = (b << 14) | ((tok0 + tg * 4 + 2) << 2) | rr_;
    }
    if (bv3 - bs3 < THRESH) {
      int ix = atomicAdd(cnt, 1);
      if (ix < MAXFLAG) flaglist[ix] = (b << 14) | ((tok0 + tg * 4 + 3) << 2) | rr_;
    }
  }
  __syncthreads();
  if (t < 128)
    ((int4*)bucket)[(size_t)b * L_ + tok0 + t] = ((int4*)sb)[t];

  // ---- emit normalized bf16 Q rows + scale (exact same reduction order) ----
  {
    int row = t >> 1, half = t & 1;   // 128 rows x 2 halves = 256 threads
    const float* qp = qs + row * 68 + half * 32;
    float v[32];
    float ss = 0.f;
    #pragma unroll
    for (int u = 0; u < 8; ++u) {
      float4 x = *(const float4*)(qp + u * 4);
      v[u*4+0] = x.x; v[u*4+1] = x.y; v[u*4+2] = x.z; v[u*4+3] = x.w;
      ss += x.x*x.x + x.y*x.y + x.z*x.z + x.w*x.w;
    }
    ss += __shfl_xor(ss, 1);
    float inv = 1.0f / fmaxf(sqrtf(ss), 1e-12f);
    unsigned short* qn = Qn + ((size_t)b * L_ + tok0 + row) * 64 + half * 32;
    #pragma unroll
    for (int u = 0; u < 4; ++u) {
      uint4 pk;
      pk.x = cvtpk(v[u*8+0] * inv, v[u*8+1] * inv);
      pk.y = cvtpk(v[u*8+2] * inv, v[u*8+3] * inv);
      pk.z = cvtpk(v[u*8+4] * inv, v[u*8+5] * inv);
      pk.w = cvtpk(v[u*8+6] * inv, v[u*8+7] * inv);
      ((uint4*)qn)[u] = pk;
    }
    if (half == 0)
      qscale[(size_t)b * L_ + tok0 + row] = 0.18033688f / inv;  // 0.125*log2e*|q|
  }

  // ---- convert this block's V rows to bf16 (adjacent-pair cvtpk) ----
  #pragma unroll
  for (int rep = 0; rep < 2; ++rep) {
    int row = (t >> 2) + rep * 64, qd = t & 3;
    const float* vr = value + ((size_t)b * L_ + tok0 + row) * DK_ + qd * 16;
    float4 x0 = ((const float4*)vr)[0], x1 = ((const float4*)vr)[1],
           x2 = ((const float4*)vr)[2], x3 = ((const float4*)vr)[3];
    uint4 p0, p1;
    p0.x = cvtpk(x0.x, x0.y); p0.y = cvtpk(x0.z, x0.w);
    p0.z = cvtpk(x1.x, x1.y); p0.w = cvtpk(x1.z, x1.w);
    p1.x = cvtpk(x2.x, x2.y); p1.y = cvtpk(x2.z, x2.w);
    p1.z = cvtpk(x3.x, x3.y); p1.w = cvtpk(x3.z, x3.w);
    unsigned short* out = Vb + ((size_t)b * L_ + tok0 + row) * 64 + qd * 16;
    ((uint4*)out)[0] = p0;
    ((uint4*)out)[1] = p1;
  }
}

// ---- Kernel 1.5: exact fp64 fixup for margin-flagged decisions --------------
__global__ __launch_bounds__(64) void fixup_kernel(
    const float* __restrict__ query, const float* __restrict__ rm,
    const int* __restrict__ flaglist, const int* __restrict__ cnt,
    int* __restrict__ bucket) {
  int nfl = *cnt;
  if (nfl > MAXFLAG) nfl = MAXFLAG;
  int lane = threadIdx.x;
  for (int i = blockIdx.x; i < nfl; i += gridDim.x) {
    int code = flaglist[i];
    int r = code & 3, l = (code >> 2) & 4095, b = code >> 14;
    int col = r * 32 + (lane & 31);
    const float* qrow = query + ((size_t)b * L_ + l) * DK_;
    const float* rmc = rm + (size_t)b * (DK_ * 128) + col;
    double acc = 0.0, ss = 0.0;
    for (int d = 0; d < DK_; ++d) {
      double qv = (double)qrow[d];
      double rv = (double)rmc[d * 128];
      acc += qv * rv;
      ss += rv * rv;
    }
    double sinv = 1.0 / sqrt(ss);
    double v = acc * sinv;
    double bv = (lane < 32) ? v : -v;
    int bi = lane;
    #pragma unroll
    for (int msk = 1; msk < 64; msk <<= 1) {
      double ov = __shfl_xor(bv, msk);
      int oi = __shfl_xor(bi, msk);
      if (ov > bv || (ov == bv && oi < bi)) { bv = ov; bi = oi; }
    }
    if (lane == 0) bucket[((size_t)b * L_ + l) * 4 + r] = bi;
  }
}

// ------- Kernel 2: 16-wave two-level stable counting sort per (b, r) --------
__global__ __launch_bounds__(1024) void sort_kernel(
    const int* __restrict__ bucket, int* __restrict__ sorted_pos,
    unsigned char* __restrict__ cpack) {
  int b = blockIdx.x >> 2;
  int r = blockIdx.x & 3;
  __shared__ int hist[64 * 65];   // [chunk][bin], stride 65
  __shared__ int off[64];
  int t = threadIdx.x, lane = t & 63, w = t >> 6;
  unsigned long long ltmask = (1ull << lane) - 1ull;
  const int* bb = bucket + (size_t)b * L_ * 4 + r;

  int binv[4], rank[4];
  #pragma unroll
  for (int u = 0; u < 4; ++u)
    binv[u] = bb[(size_t)((w * 4 + u) * 64 + lane) * 4];

  for (int idx = t; idx < 64 * 65; idx += 1024) hist[idx] = 0;
  __syncthreads();

  #pragma unroll
  for (int u = 0; u < 4; ++u) {
    int bin = binv[u];
    unsigned long long m = ~0ull;
    #pragma unroll
    for (int k = 0; k < 6; ++k) {
      unsigned long long bal = __ballot((bin >> k) & 1);
      m &= ((bin >> k) & 1) ? bal : ~bal;
    }
    rank[u] = (int)__popcll(m & ltmask);
    if (rank[u] == 0) hist[(w * 4 + u) * 65 + bin] = (int)__popcll(m);
  }
  __syncthreads();

  if (w == 0) {
    int run = 0;
    for (int g = 0; g < 64; ++g) {
      int v = hist[g * 65 + lane];
      hist[g * 65 + lane] = run;
      run += v;
    }
    int inc = run;
    #pragma unroll
    for (int d = 1; d < 64; d <<= 1) {
      int y = __shfl_up(inc, d, 64);
      if (lane >= d) inc += y;
    }
    off[lane] = inc - run;
  }
  __syncthreads();

  int* sp = sorted_pos + ((size_t)b * R_ + r) * L_;
  unsigned char* cp = cpack + (size_t)b * L_ * 4 + r;
  #pragma unroll
  for (int u = 0; u < 4; ++u) {
    int g = w * 4 + u;
    int bin = binv[u];
    int slot = off[bin] + hist[g * 65 + bin] + rank[u];
    sp[slot] = g * 64 + lane;
    cp[(size_t)(g * 64 + lane) * 4] = (unsigned char)(slot >> 6);
  }
}

// ---------------- Kernel 3: per-chunk attention (bf16 MFMA, R11 form) --------
__global__ __launch_bounds__(256) void attn_kernel(
    const unsigned short* __restrict__ Qn, const unsigned short* __restrict__ Vb,
    const float* __restrict__ qscale,
    const int* __restrict__ sorted_pos, const int* __restrict__ bucket,
    const int* __restrict__ cpack,
    unsigned short* __restrict__ att, float* __restrict__ lse_s) {
  int wg = (int)blockIdx.x;
  wg = (wg & 7) * (B_ * R_ * NB_ / 8) + (wg >> 3);   // XCD-contiguous swizzle
  int n = wg & 63;
  int r = (wg >> 6) & 3;
  int b = wg >> 8;
  int br = b * R_ + r;
  int nprev = (n + 63) & 63;

  __shared__ __align__(16) short bufK[128 * 64];   // K_norm bf16; reused as VT[64][128]
  __shared__ int skpos[128];
  __shared__ int skcode[128];                      // (bucket<<12) | pos
  __shared__ int sck[128];                         // packed chunk ids (4x8b)

  int t = threadIdx.x;
  if (t < 128) {
    int chunk = (t < 64) ? nprev : n;
    int pos = sorted_pos[(size_t)br * L_ + chunk * 64 + (t & 63)];
    skpos[t] = pos;
    skcode[t] = (bucket[((size_t)b * L_ + pos) * 4 + r] << 12) | pos;
    sck[t] = ((const int*)cpack)[(size_t)b * L_ + pos];
  }
  __syncthreads();

  int l = t & 63, w = t >> 6;
  int g = l >> 4, c = l & 15;
  int qi = w * 16 + c;

  // ---- K staging from Qn (bf16, swizzled LDS image) ----
  {
    int j = t >> 1, half = t & 1;
    const uint4* src = (const uint4*)(Qn + ((size_t)b * L_ + skpos[j]) * 64 + half * 32);
    short* krow = bufK + j * 64;
    int sz = swz(j);
    #pragma unroll
    for (int u = 0; u < 4; ++u)
      *(uint4*)(krow + (((half * 4 + u) ^ sz) << 3)) = src[u];
  }
  int qcode = skcode[64 + qi];
  int qpos = qcode & 4095;
  float csc = qscale[(size_t)b * L_ + qpos];   // issued early; used post-QK
  __syncthreads();

  // ---- QK^T via MFMA, SWAPPED: D = K_frag · Q_frag = S^T ----
  f32x4 acc[8];
  #pragma unroll
  for (int tt = 0; tt < 8; ++tt) acc[tt] = (f32x4){0.f, 0.f, 0.f, 0.f};
  {
    int qrow = 64 + qi;
    const short* qp_ = bufK + qrow * 64;
    bf16x8 q0 = *(const bf16x8*)(qp_ + (((g) ^ swz(qrow)) << 3));
    bf16x8 q1 = *(const bf16x8*)(qp_ + (((4 + g) ^ swz(qrow)) << 3));
    #pragma unroll
    for (int tt = 0; tt < 8; ++tt) {
      int krow = tt * 16 + c;
      const short* kp_ = bufK + krow * 64;
      bf16x8 k0 = *(const bf16x8*)(kp_ + (((g) ^ swz(krow)) << 3));
      bf16x8 k1 = *(const bf16x8*)(kp_ + (((4 + g) ^ swz(krow)) << 3));
      acc[tt] = __builtin_amdgcn_mfma_f32_16x16x32_bf16(k0, q0, acc[tt], 0, 0, 0);
      acc[tt] = __builtin_amdgcn_mfma_f32_16x16x32_bf16(k1, q1, acc[tt], 0, 0, 0);
    }
  }
  __syncthreads();   // all waves done reading bufK (VT will overwrite)

  // ---- issue V gathers early (bf16); consumed after softmax ----
  int pi = t >> 2, qd = t & 3;
  const uint4* vr0 = (const uint4*)(Vb + ((size_t)b * L_ + skpos[2 * pi]) * 64 + qd * 16);
  const uint4* vr1 = (const uint4*)(Vb + ((size_t)b * L_ + skpos[2 * pi + 1]) * 64 + qd * 16);
  uint4 A0 = vr0[0], A1 = vr0[1];
  uint4 B0 = vr1[0], B1 = vr1[1];

  // ---- masks + lane-local softmax (exp2 domain) ----
  unsigned aq = (unsigned)sck[64 + qi] | 0x40404040u;

  float m = -1e30f;
  #pragma unroll
  for (int tt = 0; tt < 8; ++tt) {
    int4 kc = *(const int4*)(skcode + tt * 16 + g * 4);
    #pragma unroll
    for (int j = 0; j < 4; ++j) {
      int kcode = (j == 0) ? kc.x : (j == 1) ? kc.y : (j == 2) ? kc.z : kc.w;
      float s = acc[tt][j] * csc;
      unsigned x = (unsigned)(qcode ^ kcode);
      s = ((qcode < kcode) || (x >= 4096u)) ? -1e9f : s;
      s = (x == 0u) ? -144269.5f : s;   // -1e5 * log2e
      acc[tt][j] = s;
      m = fmaxf(m, s);
    }
  }
  m = fmaxf(m, __shfl_xor(m, 16));
  m = fmaxf(m, __shfl_xor(m, 32));
  float sum = 0.f;
  #pragma unroll
  for (int tt = 0; tt < 8; ++tt) {
    #pragma unroll
    for (int j = 0; j < 4; ++j) {
      float e = exp2f(acc[tt][j] - m);
      acc[tt][j] = e;
      sum += e;
    }
  }
  sum += __shfl_xor(sum, 16);
  sum += __shfl_xor(sum, 32);
  float lse = 0.69314718f * (m + __log2f(sum));
  float isum = 1.0f / sum;
  if (l < 16) lse_s[(size_t)br * L_ + qpos] = lse;

  // ---- dup-count (SWAR) -> final P in registers ----
  #pragma unroll
  for (int tt = 0; tt < 8; ++tt) {
    int4 c4v = *(const int4*)(sck + tt * 16 + g * 4);
    #pragma unroll
    for (int j = 0; j < 4; ++j) {
      int ckv = (j == 0) ? c4v.x : (j == 1) ? c4v.y : (j == 2) ? c4v.z : c4v.w;
      unsigned e = (aq - (unsigned)ckv) & 0x3E3E3E3Eu;
      unsigned y = (e - 0x01010101u) & ~e & 0x80808080u;
      float cntf = (float)__popc(y);
      acc[tt][j] = acc[tt][j] * isum * __builtin_amdgcn_rcpf(cntf);
    }
  }

  // ---- P -> bf16 pairs in registers ----
  unsigned pk01[8], pk23[8];
  #pragma unroll
  for (int tt = 0; tt < 8; ++tt) {
    pk01[tt] = cvtpk(acc[tt][0], acc[tt][1]);
    pk23[tt] = cvtpk(acc[tt][2], acc[tt][3]);
  }

  // ---- VT staging into freed bufK (transpose from bf16 regs) ----
  short* VT = bufK;
  {
    unsigned Aw[8] = {A0.x, A0.y, A0.z, A0.w, A1.x, A1.y, A1.z, A1.w};
    unsigned Bw[8] = {B0.x, B0.y, B0.z, B0.w, B1.x, B1.y, B1.z, B1.w};
    int k0 = 2 * pi;
    #pragma unroll
    for (int i = 0; i < 8; ++i) {
      unsigned lo = (Aw[i] & 0xffffu) | (Bw[i] << 16);
      unsigned hi = (Aw[i] >> 16) | (Bw[i] & 0xffff0000u);
      int dl = qd * 16 + 2 * i, dh = dl + 1;
      *(unsigned*)(VT + dl * 128 + (((k0 >> 3) ^ swz(dl)) << 3) + (k0 & 7)) = lo;
      *(unsigned*)(VT + dh * 128 + (((k0 >> 3) ^ swz(dh)) << 3) + (k0 & 7)) = hi;
    }
  }
  __syncthreads();

  // ---- PV via MFMA: O^T[d][q] = sum_k VT[d][k] * P^T[k][q] ----
  f32x4 o[4];
  #pragma unroll
  for (int nt = 0; nt < 4; ++nt) o[nt] = (f32x4){0.f, 0.f, 0.f, 0.f};
  {
    int src  = (g & 1) * 32 + c;
    int srcB = src + 16;
    bool sel = (l >= 32);
    #pragma unroll
    for (int ks = 0; ks < 4; ++ks) {
      unsigned xA = __shfl(pk01[2 * ks], src),  yA = __shfl(pk01[2 * ks + 1], src);
      unsigned xB = __shfl(pk23[2 * ks], src),  yB = __shfl(pk23[2 * ks + 1], src);
      unsigned xC = __shfl(pk01[2 * ks], srcB), yC = __shfl(pk01[2 * ks + 1], srcB);
      unsigned xD = __shfl(pk23[2 * ks], srcB), yD = __shfl(pk23[2 * ks + 1], srcB);
      union { uint4 u; bf16x8 v; } bp;
      bp.u.x = sel ? yA : xA;
      bp.u.y = sel ? yB : xB;
      bp.u.z = sel ? yC : xC;
      bp.u.w = sel ? yD : xD;
      #pragma unroll
      for (int nt = 0; nt < 4; ++nt) {
        int vrow = nt * 16 + c;
        bf16x8 av = *(const bf16x8*)(VT + vrow * 128 + (((ks * 4 + g) ^ swz(vrow)) << 3));
        o[nt] = __builtin_amdgcn_mfma_f32_16x16x32_bf16(av, bp.v, o[nt], 0, 0, 0);
      }
    }
  }

  // ---- scatter att rows (bf16, 8B stores): lane owns one q-row ----
  {
    unsigned short* arow = att + ((size_t)br * L_ + qpos) * DK_;
    #pragma unroll
    for (int nt = 0; nt < 4; ++nt) {
      unsigned p0 = cvtpk(o[nt][0], o[nt][1]);
      unsigned p1 = cvtpk(o[nt][2], o[nt][3]);
      *(uint2*)(arow + nt * 16 + g * 4) = make_uint2(p0, p1);
    }
  }
}

// ---------------- Kernel 4: softmax reduction over L of lse ------------------
__global__ __launch_bounds__(256) void lsered_kernel(
    const float* __restrict__ lse_s, float* __restrict__ wred) {
  int br = blockIdx.x;
  const float* row = lse_s + (size_t)br * L_;
  __shared__ float red[4];
  int t = threadIdx.x;
  float m = -1e30f;
  for (int p = t; p < L_; p += 256) m = fmaxf(m, row[p]);
  #pragma unroll
  for (int mask = 1; mask < 64; mask <<= 1) m = fmaxf(m, __shfl_xor(m, mask, 64));
  if ((t & 63) == 0) red[t >> 6] = m;
  __syncthreads();
  m = fmaxf(fmaxf(red[0], red[1]), fmaxf(red[2], red[3]));
  __syncthreads();
  float sum = 0.f;
  for (int p = t; p < L_; p += 256) sum += __expf(row[p] - m);
  #pragma unroll
  for (int mask = 1; mask < 64; mask <<= 1) sum += __shfl_xor(sum, mask, 64);
  if ((t & 63) == 0) red[t >> 6] = sum;
  __syncthreads();
  if (t == 0) {
    wred[br * 2] = m;
    wred[br * 2 + 1] = red[0] + red[1] + red[2] + red[3];
  }
}

// ---------------- Kernel 5: weighted combine over rounds ---------------------
__global__ __launch_bounds__(256) void combine_kernel(
    const unsigned short* __restrict__ att, const float* __restrict__ lse_s,
    const float* __restrict__ wred, float* __restrict__ out) {
  int idx = blockIdx.x * 256 + threadIdx.x;
  int dq = idx & 3;
  int l = (idx >> 2) & (L_ - 1);
  int b = idx >> 14;
  float wv[4];
  #pragma unroll
  for (int r = 0; r < R_; ++r) {
    float m = wred[(b * R_ + r) * 2];
    float sinv = 1.0f / wred[(b * R_ + r) * 2 + 1];
    wv[r] = __expf(lse_s[((size_t)b * R_ + r) * L_ + l] - m) * sinv;
  }
  #pragma unroll
  for (int u = 0; u < 4; ++u) {
    int d4 = dq * 4 + u;
    float4 o = make_float4(0.f, 0.f, 0.f, 0.f);
    #pragma unroll
    for (int r = 0; r < R_; ++r) {
      ushort4 a = *(const ushort4*)(att + ((((size_t)b * R_ + r) * L_ + l) * 16 + d4) * 4);
      o.x += wv[r] * bf2f(a.x); o.y += wv[r] * bf2f(a.y);
      o.z += wv[r] * bf2f(a.z); o.w += wv[r] * bf2f(a.w);
    }
    ((float4*)out)[((size_t)b * L_ + l) * 16 + d4] = o;
  }
}

extern "C" void kernel_launch(void* const* d_in, const int* in_sizes, int n_in,
                              void* d_out, int out_size, void* d_ws, size_t ws_size,
                              hipStream_t stream) {
  const float* query = (const float*)d_in[0];
  const float* value = (const float*)d_in[1];
  const float* rm    = (const float*)d_in[2];
  (void)in_sizes; (void)n_in; (void)out_size; (void)ws_size;

  char* ws = (char*)d_ws;
  const size_t ATT_BYTES = (size_t)B_ * R_ * L_ * DK_ * 2;  // 32 MiB (bf16)
  const size_t MB = 1048576;
  unsigned short* att        = (unsigned short*)ws;
  int*            bucket     = (int*)(ws + ATT_BYTES);
  int*            sorted_pos = (int*)(ws + ATT_BYTES + 1 * MB);
  unsigned char*  cpack      = (unsigned char*)(ws + ATT_BYTES + 2 * MB);
  float*          lse_s      = (float*)(ws + ATT_BYTES + 3 * MB);
  float*          wred       = (float*)(ws + ATT_BYTES + 4 * MB);
  float*          qscale     = (float*)(ws + ATT_BYTES + 6 * MB);
  unsigned short* Qn         = (unsigned short*)(ws + ATT_BYTES + 8 * MB);
  unsigned short* Vb         = (unsigned short*)(ws + ATT_BYTES + 16 * MB);
  int*            cnt        = (int*)(ws + ATT_BYTES + 24 * MB);
  int*            flaglist   = (int*)(ws + ATT_BYTES + 25 * MB);
  float* out = (float*)d_out;

  zc_kernel<<<1, 1, 0, stream>>>(cnt);
  hash_kernel<<<B_ * 32, 256, 0, stream>>>(query, value, rm, bucket, Qn, qscale,
                                           Vb, cnt, flaglist);
  fixup_kernel<<<4096, 64, 0, stream>>>(query, rm, flaglist, cnt, bucket);
  sort_kernel<<<B_ * R_, 1024, 0, stream>>>(bucket, sorted_pos, cpack);
  attn_kernel<<<B_ * R_ * NB_, 256, 0, stream>>>(Qn, Vb, qscale, sorted_pos,
                                                 bucket, (const int*)cpack,
                                                 att, lse_s);
  lsered_kernel<<<B_ * R_, 256, 0, stream>>>(lse_s, wred);
  combine_kernel<<<(B_ * L_ * 4) / 256, 256, 0, stream>>>(att, lse_s, wred, out);
}

// Round 21
// 104.414 us; speedup vs baseline: 10.1911x; 1.1160x over previous
//
#include <hip/hip_runtime.h>

#define B_ 16
#define L_ 4096
#define DK_ 64
#define R_ 4
#define NB_ 64
#define BL_ 64

typedef __attribute__((ext_vector_type(8))) short bf16x8;
typedef __attribute__((ext_vector_type(4))) float f32x4;

__device__ __forceinline__ float bf2f(unsigned short u) {
  return __uint_as_float(((unsigned)u) << 16);
}
// HW packed f32->bf16 (RNE) — 1 inst per 2 values
__device__ __forceinline__ unsigned cvtpk(float lo, float hi) {
  unsigned r;
  asm("v_cvt_pk_bf16_f32 %0, %1, %2" : "=v"(r) : "v"(lo), "v"(hi));
  return r;
}
__device__ __forceinline__ int swz(int row) { return (row & 7) ^ ((row >> 3) & 7); }

// ---- Kernel 1: LSH hashing — fp64 vector, 2x16 register tile ---------------
// 64 tokens/block; rs staged in TWO half-d passes (20.5KB) so total LDS
// 39.9KB -> 4 blocks/CU. fp64 per-(tok,col) chains stay d-ascending
// across the two passes -> bit-identical buckets. Emits Qn/qscale/Vb.
__global__ __launch_bounds__(256) void hash_kernel(
    const float* __restrict__ query, const float* __restrict__ value,
    const float* __restrict__ rm, int* __restrict__ bucket,
    unsigned short* __restrict__ Qn, float* __restrict__ qscale,
    unsigned short* __restrict__ Vb) {
  __shared__ float qs[64 * 68];      // q[tok][d], stride 68   (17408B)
  __shared__ float rs[32 * 160];     // rm half-d [32][cg*20]  (20480B)
  __shared__ double ssin[128];       // (1024B)
  __shared__ int sb[64 * 4];         // (1024B)

  int b = blockIdx.x >> 6;
  int tok0 = (blockIdx.x & 63) << 6;   // 64 tokens per block
  int t = threadIdx.x;

  {  // stage q: 64 tok x 16 float4
    const float4* qg = (const float4*)(query + ((size_t)b * L_ + tok0) * DK_);
    #pragma unroll
    for (int u = 0; u < 4; ++u) {
      int i = t + u * 256;
      int tokl = i >> 4, c4 = i & 15;
      *(float4*)(qs + tokl * 68 + c4 * 4) = qg[i];
    }
  }
  {  // stage rm rows d = 0..31 into padded-cg layout
    const float4* rg = (const float4*)(rm + (size_t)b * (DK_ * 128));
    #pragma unroll
    for (int u = 0; u < 4; ++u) {
      int i = t + u * 256;            // 1024 float4s, d = i>>5 in [0,32)
      int d = i >> 5, c4 = i & 31;
      int cg2 = c4 >> 2, j4 = c4 & 3;
      *(float4*)(rs + d * 160 + cg2 * 20 + j4 * 4) = rg[i];
    }
  }
  __syncthreads();

  // ssin partial over d = 0..31 (fp64, ascending)
  double ssp = 0.0;
  if (t < 128) {
    const float* colp = rs + (t >> 4) * 20 + (t & 15);
    for (int d = 0; d < 32; ++d) {
      double v = (double)colp[d * 160];
      ssp += v * v;
    }
  }

  int cg = t & 7;
  int tg = t >> 3;
  double acc0[16], acc1[16];
  #pragma unroll
  for (int j = 0; j < 16; ++j) { acc0[j] = 0.0; acc1[j] = 0.0; }

  const float* q0 = qs + (tg * 2 + 0) * 68;
  const float* q1 = qs + (tg * 2 + 1) * 68;
  const float* rp = rs + cg * 20;

  // ---- acc part 1: d = 0..31 ----
  for (int d4 = 0; d4 < 8; ++d4) {
    float4 qa4 = *(const float4*)(q0 + d4 * 4);
    float4 qb4 = *(const float4*)(q1 + d4 * 4);
    #pragma unroll
    for (int sub = 0; sub < 4; ++sub) {
      double qa = (double)((sub == 0) ? qa4.x : (sub == 1) ? qa4.y : (sub == 2) ? qa4.z : qa4.w);
      double qb = (double)((sub == 0) ? qb4.x : (sub == 1) ? qb4.y : (sub == 2) ? qb4.z : qb4.w);
      const float* rr = rp + (d4 * 4 + sub) * 160;
      #pragma unroll
      for (int j4 = 0; j4 < 4; ++j4) {
        float4 rv = *(const float4*)(rr + j4 * 4);
        double r0 = (double)rv.x, r1 = (double)rv.y,
               r2 = (double)rv.z, r3 = (double)rv.w;
        acc0[j4 * 4 + 0] += qa * r0; acc0[j4 * 4 + 1] += qa * r1;
        acc0[j4 * 4 + 2] += qa * r2; acc0[j4 * 4 + 3] += qa * r3;
        acc1[j4 * 4 + 0] += qb * r0; acc1[j4 * 4 + 1] += qb * r1;
        acc1[j4 * 4 + 2] += qb * r2; acc1[j4 * 4 + 3] += qb * r3;
      }
    }
  }
  __syncthreads();   // everyone done reading rs half 1

  {  // stage rm rows d = 32..63
    const float4* rg = (const float4*)(rm + (size_t)b * (DK_ * 128)) + 1024;
    #pragma unroll
    for (int u = 0; u < 4; ++u) {
      int i = t + u * 256;
      int d = i >> 5, c4 = i & 31;
      int cg2 = c4 >> 2, j4 = c4 & 3;
      *(float4*)(rs + d * 160 + cg2 * 20 + j4 * 4) = rg[i];
    }
  }
  __syncthreads();

  // ssin finish over d = 32..63 (same ascending chain)
  if (t < 128) {
    const float* colp = rs + (t >> 4) * 20 + (t & 15);
    for (int d = 0; d < 32; ++d) {
      double v = (double)colp[d * 160];
      ssp += v * v;
    }
    ssin[t] = 1.0 / sqrt(ssp);
  }

  // ---- acc part 2: d = 32..63 (rs rows hold d-32) ----
  for (int d4 = 8; d4 < 16; ++d4) {
    float4 qa4 = *(const float4*)(q0 + d4 * 4);
    float4 qb4 = *(const float4*)(q1 + d4 * 4);
    #pragma unroll
    for (int sub = 0; sub < 4; ++sub) {
      double qa = (double)((sub == 0) ? qa4.x : (sub == 1) ? qa4.y : (sub == 2) ? qa4.z : qa4.w);
      double qb = (double)((sub == 0) ? qb4.x : (sub == 1) ? qb4.y : (sub == 2) ? qb4.z : qb4.w);
      const float* rr = rp + ((d4 - 8) * 4 + sub) * 160;
      #pragma unroll
      for (int j4 = 0; j4 < 4; ++j4) {
        float4 rv = *(const float4*)(rr + j4 * 4);
        double r0 = (double)rv.x, r1 = (double)rv.y,
               r2 = (double)rv.z, r3 = (double)rv.w;
        acc0[j4 * 4 + 0] += qa * r0; acc0[j4 * 4 + 1] += qa * r1;
        acc0[j4 * 4 + 2] += qa * r2; acc0[j4 * 4 + 3] += qa * r3;
        acc1[j4 * 4 + 0] += qb * r0; acc1[j4 * 4 + 1] += qb * r1;
        acc1[j4 * 4 + 2] += qb * r2; acc1[j4 * 4 + 3] += qb * r3;
      }
    }
  }
  __syncthreads();   // ssin final visible to all

  double bv0 = -1e300, bv1 = -1e300;
  int bi0 = 0, bi1 = 0;
  int nbase = (cg & 1) * 16;
  #pragma unroll
  for (int j = 0; j < 16; ++j) {
    int col = cg * 16 + j;
    double sv = ssin[col];
    int n = nbase + j;
    double v0 = acc0[j] * sv;
    double v1 = acc1[j] * sv;
    if (v0 > bv0 || (v0 == bv0 && n < bi0)) { bv0 = v0; bi0 = n; }
    if (-v0 > bv0 || (-v0 == bv0 && n + 32 < bi0)) { bv0 = -v0; bi0 = n + 32; }
    if (v1 > bv1 || (v1 == bv1 && n < bi1)) { bv1 = v1; bi1 = n; }
    if (-v1 > bv1 || (-v1 == bv1 && n + 32 < bi1)) { bv1 = -v1; bi1 = n + 32; }
  }
  {
    double ov = __shfl_xor(bv0, 1);
    int oi = __shfl_xor(bi0, 1);
    if (ov > bv0 || (ov == bv0 && oi < bi0)) { bv0 = ov; bi0 = oi; }
    ov = __shfl_xor(bv1, 1);
    oi = __shfl_xor(bi1, 1);
    if (ov > bv1 || (ov == bv1 && oi < bi1)) { bv1 = ov; bi1 = oi; }
  }
  if ((cg & 1) == 0) {
    int rr_ = cg >> 1;
    sb[(tg * 2 + 0) * 4 + rr_] = bi0;
    sb[(tg * 2 + 1) * 4 + rr_] = bi1;
  }
  __syncthreads();
  if (t < 64)
    ((int4*)bucket)[(size_t)b * L_ + tok0 + t] = ((int4*)sb)[t];

  // ---- emit normalized bf16 Q rows + scale (exact same reduction order) ----
  if (t < 128) {
    int row = t >> 1, half = t & 1;
    const float* qp = qs + row * 68 + half * 32;
    float v[32];
    float ss = 0.f;
    #pragma unroll
    for (int u = 0; u < 8; ++u) {
      float4 x = *(const float4*)(qp + u * 4);
      v[u*4+0] = x.x; v[u*4+1] = x.y; v[u*4+2] = x.z; v[u*4+3] = x.w;
      ss += x.x*x.x + x.y*x.y + x.z*x.z + x.w*x.w;
    }
    ss += __shfl_xor(ss, 1);
    float inv = 1.0f / fmaxf(sqrtf(ss), 1e-12f);
    unsigned short* qn = Qn + ((size_t)b * L_ + tok0 + row) * 64 + half * 32;
    #pragma unroll
    for (int u = 0; u < 4; ++u) {
      uint4 pk;
      pk.x = cvtpk(v[u*8+0] * inv, v[u*8+1] * inv);
      pk.y = cvtpk(v[u*8+2] * inv, v[u*8+3] * inv);
      pk.z = cvtpk(v[u*8+4] * inv, v[u*8+5] * inv);
      pk.w = cvtpk(v[u*8+6] * inv, v[u*8+7] * inv);
      ((uint4*)qn)[u] = pk;
    }
    if (half == 0)
      qscale[(size_t)b * L_ + tok0 + row] = 0.18033688f / inv;  // 0.125*log2e*|q|
  }

  // ---- convert this block's V rows to bf16 (adjacent-pair cvtpk) ----
  {
    int row = t >> 2, qd = t & 3;
    const float* vr = value + ((size_t)b * L_ + tok0 + row) * DK_ + qd * 16;
    float4 x0 = ((const float4*)vr)[0], x1 = ((const float4*)vr)[1],
           x2 = ((const float4*)vr)[2], x3 = ((const float4*)vr)[3];
    uint4 p0, p1;
    p0.x = cvtpk(x0.x, x0.y); p0.y = cvtpk(x0.z, x0.w);
    p0.z = cvtpk(x1.x, x1.y); p0.w = cvtpk(x1.z, x1.w);
    p1.x = cvtpk(x2.x, x2.y); p1.y = cvtpk(x2.z, x2.w);
    p1.z = cvtpk(x3.x, x3.y); p1.w = cvtpk(x3.z, x3.w);
    unsigned short* out = Vb + ((size_t)b * L_ + tok0 + row) * 64 + qd * 16;
    ((uint4*)out)[0] = p0;
    ((uint4*)out)[1] = p1;
  }
}

// ------- Kernel 2: 16-wave two-level stable counting sort per (b, r) --------
__global__ __launch_bounds__(1024) void sort_kernel(
    const int* __restrict__ bucket, int* __restrict__ sorted_pos,
    unsigned char* __restrict__ cpack) {
  int b = blockIdx.x >> 2;
  int r = blockIdx.x & 3;
  __shared__ int hist[64 * 65];   // [chunk][bin], stride 65
  __shared__ int off[64];
  int t = threadIdx.x, lane = t & 63, w = t >> 6;
  unsigned long long ltmask = (1ull << lane) - 1ull;
  const int* bb = bucket + (size_t)b * L_ * 4 + r;

  int binv[4], rank[4];
  #pragma unroll
  for (int u = 0; u < 4; ++u)
    binv[u] = bb[(size_t)((w * 4 + u) * 64 + lane) * 4];

  for (int idx = t; idx < 64 * 65; idx += 1024) hist[idx] = 0;
  __syncthreads();

  #pragma unroll
  for (int u = 0; u < 4; ++u) {
    int bin = binv[u];
    unsigned long long m = ~0ull;
    #pragma unroll
    for (int k = 0; k < 6; ++k) {
      unsigned long long bal = __ballot((bin >> k) & 1);
      m &= ((bin >> k) & 1) ? bal : ~bal;
    }
    rank[u] = (int)__popcll(m & ltmask);
    if (rank[u] == 0) hist[(w * 4 + u) * 65 + bin] = (int)__popcll(m);
  }
  __syncthreads();

  if (w == 0) {
    int run = 0;
    for (int g = 0; g < 64; ++g) {
      int v = hist[g * 65 + lane];
      hist[g * 65 + lane] = run;
      run += v;
    }
    int inc = run;
    #pragma unroll
    for (int d = 1; d < 64; d <<= 1) {
      int y = __shfl_up(inc, d, 64);
      if (lane >= d) inc += y;
    }
    off[lane] = inc - run;
  }
  __syncthreads();

  int* sp = sorted_pos + ((size_t)b * R_ + r) * L_;
  unsigned char* cp = cpack + (size_t)b * L_ * 4 + r;
  #pragma unroll
  for (int u = 0; u < 4; ++u) {
    int g = w * 4 + u;
    int bin = binv[u];
    int slot = off[bin] + hist[g * 65 + bin] + rank[u];
    sp[slot] = g * 64 + lane;
    cp[(size_t)(g * 64 + lane) * 4] = (unsigned char)(slot >> 6);
  }
}

// ---------------- Kernel 3: per-chunk attention (bf16 MFMA, R11 form) --------
__global__ __launch_bounds__(256) void attn_kernel(
    const unsigned short* __restrict__ Qn, const unsigned short* __restrict__ Vb,
    const float* __restrict__ qscale,
    const int* __restrict__ sorted_pos, const int* __restrict__ bucket,
    const int* __restrict__ cpack,
    unsigned short* __restrict__ att, float* __restrict__ lse_s) {
  int wg = (int)blockIdx.x;
  wg = (wg & 7) * (B_ * R_ * NB_ / 8) + (wg >> 3);   // XCD-contiguous swizzle
  int n = wg & 63;
  int r = (wg >> 6) & 3;
  int b = wg >> 8;
  int br = b * R_ + r;
  int nprev = (n + 63) & 63;

  __shared__ __align__(16) short bufK[128 * 64];   // K_norm bf16; reused as VT[64][128]
  __shared__ int skpos[128];
  __shared__ int skcode[128];                      // (bucket<<12) | pos
  __shared__ int sck[128];                         // packed chunk ids (4x8b)

  int t = threadIdx.x;
  if (t < 128) {
    int chunk = (t < 64) ? nprev : n;
    int pos = sorted_pos[(size_t)br * L_ + chunk * 64 + (t & 63)];
    skpos[t] = pos;
    skcode[t] = (bucket[((size_t)b * L_ + pos) * 4 + r] << 12) | pos;
    sck[t] = ((const int*)cpack)[(size_t)b * L_ + pos];
  }
  __syncthreads();

  int l = t & 63, w = t >> 6;
  int g = l >> 4, c = l & 15;
  int qi = w * 16 + c;

  // ---- K staging from Qn (bf16, swizzled LDS image) ----
  {
    int j = t >> 1, half = t & 1;
    const uint4* src = (const uint4*)(Qn + ((size_t)b * L_ + skpos[j]) * 64 + half * 32);
    short* krow = bufK + j * 64;
    int sz = swz(j);
    #pragma unroll
    for (int u = 0; u < 4; ++u)
      *(uint4*)(krow + (((half * 4 + u) ^ sz) << 3)) = src[u];
  }
  int qcode = skcode[64 + qi];
  int qpos = qcode & 4095;
  float csc = qscale[(size_t)b * L_ + qpos];   // issued early; used post-QK
  __syncthreads();

  // ---- QK^T via MFMA, SWAPPED: D = K_frag · Q_frag = S^T ----
  f32x4 acc[8];
  #pragma unroll
  for (int tt = 0; tt < 8; ++tt) acc[tt] = (f32x4){0.f, 0.f, 0.f, 0.f};
  {
    int qrow = 64 + qi;
    const short* qp_ = bufK + qrow * 64;
    bf16x8 q0 = *(const bf16x8*)(qp_ + (((g) ^ swz(qrow)) << 3));
    bf16x8 q1 = *(const bf16x8*)(qp_ + (((4 + g) ^ swz(qrow)) << 3));
    #pragma unroll
    for (int tt = 0; tt < 8; ++tt) {
      int krow = tt * 16 + c;
      const short* kp_ = bufK + krow * 64;
      bf16x8 k0 = *(const bf16x8*)(kp_ + (((g) ^ swz(krow)) << 3));
      bf16x8 k1 = *(const bf16x8*)(kp_ + (((4 + g) ^ swz(krow)) << 3));
      acc[tt] = __builtin_amdgcn_mfma_f32_16x16x32_bf16(k0, q0, acc[tt], 0, 0, 0);
      acc[tt] = __builtin_amdgcn_mfma_f32_16x16x32_bf16(k1, q1, acc[tt], 0, 0, 0);
    }
  }
  __syncthreads();   // all waves done reading bufK (VT will overwrite)

  // ---- issue V gathers early (bf16); consumed after softmax ----
  int pi = t >> 2, qd = t & 3;
  const uint4* vr0 = (const uint4*)(Vb + ((size_t)b * L_ + skpos[2 * pi]) * 64 + qd * 16);
  const uint4* vr1 = (const uint4*)(Vb + ((size_t)b * L_ + skpos[2 * pi + 1]) * 64 + qd * 16);
  uint4 A0 = vr0[0], A1 = vr0[1];
  uint4 B0 = vr1[0], B1 = vr1[1];

  // ---- masks + lane-local softmax (exp2 domain) ----
  unsigned aq = (unsigned)sck[64 + qi] | 0x40404040u;

  float m = -1e30f;
  #pragma unroll
  for (int tt = 0; tt < 8; ++tt) {
    int4 kc = *(const int4*)(skcode + tt * 16 + g * 4);
    #pragma unroll
    for (int j = 0; j < 4; ++j) {
      int kcode = (j == 0) ? kc.x : (j == 1) ? kc.y : (j == 2) ? kc.z : kc.w;
      float s = acc[tt][j] * csc;
      unsigned x = (unsigned)(qcode ^ kcode);
      s = ((qcode < kcode) || (x >= 4096u)) ? -1e9f : s;
      s = (x == 0u) ? -144269.5f : s;   // -1e5 * log2e
      acc[tt][j] = s;
      m = fmaxf(m, s);
    }
  }
  m = fmaxf(m, __shfl_xor(m, 16));
  m = fmaxf(m, __shfl_xor(m, 32));
  float sum = 0.f;
  #pragma unroll
  for (int tt = 0; tt < 8; ++tt) {
    #pragma unroll
    for (int j = 0; j < 4; ++j) {
      float e = exp2f(acc[tt][j] - m);
      acc[tt][j] = e;
      sum += e;
    }
  }
  sum += __shfl_xor(sum, 16);
  sum += __shfl_xor(sum, 32);
  float lse = 0.69314718f * (m + __log2f(sum));
  float isum = 1.0f / sum;
  if (l < 16) lse_s[(size_t)br * L_ + qpos] = lse;

  // ---- dup-count (SWAR) -> final P in registers ----
  #pragma unroll
  for (int tt = 0; tt < 8; ++tt) {
    int4 c4v = *(const int4*)(sck + tt * 16 + g * 4);
    #pragma unroll
    for (int j = 0; j < 4; ++j) {
      int ckv = (j == 0) ? c4v.x : (j == 1) ? c4v.y : (j == 2) ? c4v.z : c4v.w;
      unsigned e = (aq - (unsigned)ckv) & 0x3E3E3E3Eu;
      unsigned y = (e - 0x01010101u) & ~e & 0x80808080u;
      float cntf = (float)__popc(y);
      acc[tt][j] = acc[tt][j] * isum * __builtin_amdgcn_rcpf(cntf);
    }
  }

  // ---- P -> bf16 pairs in registers ----
  unsigned pk01[8], pk23[8];
  #pragma unroll
  for (int tt = 0; tt < 8; ++tt) {
    pk01[tt] = cvtpk(acc[tt][0], acc[tt][1]);
    pk23[tt] = cvtpk(acc[tt][2], acc[tt][3]);
  }

  // ---- VT staging into freed bufK (transpose from bf16 regs) ----
  short* VT = bufK;
  {
    unsigned Aw[8] = {A0.x, A0.y, A0.z, A0.w, A1.x, A1.y, A1.z, A1.w};
    unsigned Bw[8] = {B0.x, B0.y, B0.z, B0.w, B1.x, B1.y, B1.z, B1.w};
    int k0 = 2 * pi;
    #pragma unroll
    for (int i = 0; i < 8; ++i) {
      unsigned lo = (Aw[i] & 0xffffu) | (Bw[i] << 16);
      unsigned hi = (Aw[i] >> 16) | (Bw[i] & 0xffff0000u);
      int dl = qd * 16 + 2 * i, dh = dl + 1;
      *(unsigned*)(VT + dl * 128 + (((k0 >> 3) ^ swz(dl)) << 3) + (k0 & 7)) = lo;
      *(unsigned*)(VT + dh * 128 + (((k0 >> 3) ^ swz(dh)) << 3) + (k0 & 7)) = hi;
    }
  }
  __syncthreads();

  // ---- PV via MFMA: O^T[d][q] = sum_k VT[d][k] * P^T[k][q] ----
  f32x4 o[4];
  #pragma unroll
  for (int nt = 0; nt < 4; ++nt) o[nt] = (f32x4){0.f, 0.f, 0.f, 0.f};
  {
    int src  = (g & 1) * 32 + c;
    int srcB = src + 16;
    bool sel = (l >= 32);
    #pragma unroll
    for (int ks = 0; ks < 4; ++ks) {
      unsigned xA = __shfl(pk01[2 * ks], src),  yA = __shfl(pk01[2 * ks + 1], src);
      unsigned xB = __shfl(pk23[2 * ks], src),  yB = __shfl(pk23[2 * ks + 1], src);
      unsigned xC = __shfl(pk01[2 * ks], srcB), yC = __shfl(pk01[2 * ks + 1], srcB);
      unsigned xD = __shfl(pk23[2 * ks], srcB), yD = __shfl(pk23[2 * ks + 1], srcB);
      union { uint4 u; bf16x8 v; } bp;
      bp.u.x = sel ? yA : xA;
      bp.u.y = sel ? yB : xB;
      bp.u.z = sel ? yC : xC;
      bp.u.w = sel ? yD : xD;
      #pragma unroll
      for (int nt = 0; nt < 4; ++nt) {
        int vrow = nt * 16 + c;
        bf16x8 av = *(const bf16x8*)(VT + vrow * 128 + (((ks * 4 + g) ^ swz(vrow)) << 3));
        o[nt] = __builtin_amdgcn_mfma_f32_16x16x32_bf16(av, bp.v, o[nt], 0, 0, 0);
      }
    }
  }

  // ---- scatter att rows (bf16, 8B stores): lane owns one q-row ----
  {
    unsigned short* arow = att + ((size_t)br * L_ + qpos) * DK_;
    #pragma unroll
    for (int nt = 0; nt < 4; ++nt) {
      unsigned p0 = cvtpk(o[nt][0], o[nt][1]);
      unsigned p1 = cvtpk(o[nt][2], o[nt][3]);
      *(uint2*)(arow + nt * 16 + g * 4) = make_uint2(p0, p1);
    }
  }
}

// ---------------- Kernel 4: softmax reduction over L of lse ------------------
__global__ __launch_bounds__(256) void lsered_kernel(
    const float* __restrict__ lse_s, float* __restrict__ wred) {
  int br = blockIdx.x;
  const float* row = lse_s + (size_t)br * L_;
  __shared__ float red[4];
  int t = threadIdx.x;
  float m = -1e30f;
  for (int p = t; p < L_; p += 256) m = fmaxf(m, row[p]);
  #pragma unroll
  for (int mask = 1; mask < 64; mask <<= 1) m = fmaxf(m, __shfl_xor(m, mask, 64));
  if ((t & 63) == 0) red[t >> 6] = m;
  __syncthreads();
  m = fmaxf(fmaxf(red[0], red[1]), fmaxf(red[2], red[3]));
  __syncthreads();
  float sum = 0.f;
  for (int p = t; p < L_; p += 256) sum += __expf(row[p] - m);
  #pragma unroll
  for (int mask = 1; mask < 64; mask <<= 1) sum += __shfl_xor(sum, mask, 64);
  if ((t & 63) == 0) red[t >> 6] = sum;
  __syncthreads();
  if (t == 0) {
    wred[br * 2] = m;
    wred[br * 2 + 1] = red[0] + red[1] + red[2] + red[3];
  }
}

// ---------------- Kernel 5: weighted combine over rounds ---------------------
__global__ __launch_bounds__(256) void combine_kernel(
    const unsigned short* __restrict__ att, const float* __restrict__ lse_s,
    const float* __restrict__ wred, float* __restrict__ out) {
  int idx = blockIdx.x * 256 + threadIdx.x;
  int dq = idx & 3;
  int l = (idx >> 2) & (L_ - 1);
  int b = idx >> 14;
  float wv[4];
  #pragma unroll
  for (int r = 0; r < R_; ++r) {
    float m = wred[(b * R_ + r) * 2];
    float sinv = 1.0f / wred[(b * R_ + r) * 2 + 1];
    wv[r] = __expf(lse_s[((size_t)b * R_ + r) * L_ + l] - m) * sinv;
  }
  #pragma unroll
  for (int u = 0; u < 4; ++u) {
    int d4 = dq * 4 + u;
    float4 o = make_float4(0.f, 0.f, 0.f, 0.f);
    #pragma unroll
    for (int r = 0; r < R_; ++r) {
      ushort4 a = *(const ushort4*)(att + ((((size_t)b * R_ + r) * L_ + l) * 16 + d4) * 4);
      o.x += wv[r] * bf2f(a.x); o.y += wv[r] * bf2f(a.y);
      o.z += wv[r] * bf2f(a.z); o.w += wv[r] * bf2f(a.w);
    }
    ((float4*)out)[((size_t)b * L_ + l) * 16 + d4] = o;
  }
}

extern "C" void kernel_launch(void* const* d_in, const int* in_sizes, int n_in,
                              void* d_out, int out_size, void* d_ws, size_t ws_size,
                              hipStream_t stream) {
  const float* query = (const float*)d_in[0];
  const float* value = (const float*)d_in[1];
  const float* rm    = (const float*)d_in[2];
  (void)in_sizes; (void)n_in; (void)out_size; (void)ws_size;

  char* ws = (char*)d_ws;
  const size_t ATT_BYTES = (size_t)B_ * R_ * L_ * DK_ * 2;  // 32 MiB (bf16)
  const size_t MB = 1048576;
  unsigned short* att        = (unsigned short*)ws;
  int*            bucket     = (int*)(ws + ATT_BYTES);
  int*            sorted_pos = (int*)(ws + ATT_BYTES + 1 * MB);
  unsigned char*  cpack      = (unsigned char*)(ws + ATT_BYTES + 2 * MB);
  float*          lse_s      = (float*)(ws + ATT_BYTES + 3 * MB);
  float*          wred       = (float*)(ws + ATT_BYTES + 4 * MB);
  float*          qscale     = (float*)(ws + ATT_BYTES + 6 * MB);
  unsigned short* Qn         = (unsigned short*)(ws + ATT_BYTES + 8 * MB);
  unsigned short* Vb         = (unsigned short*)(ws + ATT_BYTES + 16 * MB);
  float* out = (float*)d_out;

  hash_kernel<<<B_ * 64, 256, 0, stream>>>(query, value, rm, bucket, Qn, qscale, Vb);
  sort_kernel<<<B_ * R_, 1024, 0, stream>>>(bucket, sorted_pos, cpack);
  attn_kernel<<<B_ * R_ * NB_, 256, 0, stream>>>(Qn, Vb, qscale, sorted_pos,
                                                 bucket, (const int*)cpack,
                                                 att, lse_s);
  lsered_kernel<<<B_ * R_, 256, 0, stream>>>(lse_s, wred);
  combine_kernel<<<(B_ * L_ * 4) / 256, 256, 0, stream>>>(att, lse_s, wred, out);
}